// Round 16
// baseline (125.677 us; speedup 1.0000x reference)
//
#include <hip/hip_runtime.h>
#include <hip/hip_bf16.h>

typedef __bf16 bf16;
typedef __bf16 bf16x4 __attribute__((ext_vector_type(4)));
typedef __bf16 bf16x8 __attribute__((ext_vector_type(8)));
typedef float f32x2 __attribute__((ext_vector_type(2)));
typedef float f32x4 __attribute__((ext_vector_type(4)));
typedef float f32x16 __attribute__((ext_vector_type(16)));
typedef unsigned int u32x4 __attribute__((ext_vector_type(4)));

#define NH 16
#define HD 64
#define SEQ 2048
#define DM 1024
#define MTOT 4096   // B*S

__device__ __forceinline__ void gload_lds16(const void* g, void* l) {
  __builtin_amdgcn_global_load_lds(
      (const __attribute__((address_space(1))) void*)g,
      (__attribute__((address_space(3))) void*)l, 16, 0, 0);
}

// ---------------- fused prep: x->bf16, 4 weights->bf16, RoPE table ----------------
__global__ __launch_bounds__(256) void prep_kernel(
    const float* __restrict__ x,
    const float* __restrict__ w0, const float* __restrict__ w1,
    const float* __restrict__ w2, const float* __restrict__ w3,
    const int* __restrict__ pos,
    bf16* __restrict__ xb, bf16* __restrict__ wb, float2* __restrict__ tab)
{
  int i = blockIdx.x * 256 + threadIdx.x;
  if (i < 1048576) {
    float4 v = reinterpret_cast<const float4*>(x)[i];
    bf16x4 o;
    o[0] = (bf16)v.x; o[1] = (bf16)v.y; o[2] = (bf16)v.z; o[3] = (bf16)v.w;
    *reinterpret_cast<bf16x4*>(xb + (size_t)i * 4) = o;
  } else if (i < 2097152) {
    int k = i - 1048576;
    int seg = k >> 18, j = k & 262143;
    const float* src = seg == 0 ? w0 : seg == 1 ? w1 : seg == 2 ? w2 : w3;
    float4 v = reinterpret_cast<const float4*>(src)[j];
    bf16x4 o;
    o[0] = (bf16)v.x; o[1] = (bf16)v.y; o[2] = (bf16)v.z; o[3] = (bf16)v.w;
    *reinterpret_cast<bf16x4*>(wb + ((size_t)seg << 20) + (size_t)j * 4) = o;
  } else if (i < 2097152 + 131072) {
    int k = i - 2097152;
    int m = k >> 5, i2 = k & 31;
    float pf = (float)pos[m];
    float inv = 1.0f / powf(10000.0f, (float)(2 * i2) * (1.0f / 64.0f));
    float a = pf * inv;
    tab[k] = make_float2(cosf(a), sinf(a));
  }
}

// ---------------- fused QKV projection GEMM, 256x256 tile, BK=64, 8-PHASE ----------------
// (frozen — verified r9/r11) grid (12, 16): proj = x>>2, n0 = (x&3)*256.
__global__ __launch_bounds__(512, 2) void gemm_qkv(
    const bf16* __restrict__ A, const bf16* __restrict__ wAll,
    bf16* __restrict__ outq, bf16* __restrict__ outk, bf16* __restrict__ outv,
    const float2* __restrict__ tab)
{
  __shared__ bf16 ABlds[2][2][2][8192];   // [A=0/B=1][parity][kk] 256x32 bf16 = 16 KB
  const int t = threadIdx.x;
  const int w = t >> 6;
  const int wm = w >> 2, wn = w & 3;
  const int lane = t & 63;
  const int lr = lane & 15;
  const int lg = lane >> 4;
  const int m0 = blockIdx.y * 256;
  const int proj = blockIdx.x >> 2;
  const int n0l = (blockIdx.x & 3) * 256;
  const char* Asrc = (const char*)A + (size_t)m0 * 2048;
  const char* Bsrc = (const char*)(wAll + ((size_t)proj << 20) + (size_t)n0l * DM);

  f32x4 acc[8][4] = {};
  bf16x8 bfr[4];

#define REG(AB_, PAR_, KK_) ((char*)ABlds + (((AB_)*4 + (PAR_)*2 + (KK_)) * 16384))

#define STAGE_HALF(AB_, T_, KK_)                                                   \
  {                                                                                \
    const char* gb_ = (AB_) ? Bsrc : Asrc;                                         \
    char* lb_ = REG(AB_, (T_) & 1, KK_);                                           \
    _Pragma("unroll")                                                              \
    for (int p_ = 0; p_ < 2; ++p_) {                                               \
      int o_ = (p_ * 512 + t) * 16;                                                \
      int r_ = o_ >> 6, c_ = o_ & 63;                                              \
      int cs_ = c_ ^ (((r_ >> 1) & 3) << 4);                                       \
      gload_lds16(gb_ + (size_t)r_ * 2048 + (T_) * 128 + (KK_) * 64 + cs_,         \
                  lb_ + o_);                                                       \
    }                                                                              \
  }

#define RDFRAG(DST, REGP, ROW)                                                     \
  {                                                                                \
    int row_ = (ROW);                                                              \
    int cb_ = (lg * 16) ^ (((row_ >> 1) & 3) << 4);                                \
    DST = *reinterpret_cast<const bf16x8*>((REGP) + row_ * 64 + cb_);              \
  }

#define PHASE(PAR, KK, MH, DOSTAGE, S_AB, S_T, S_KK, VM)                           \
  {                                                                                \
    bf16x8 af_[4];                                                                 \
    const char* areg_ = REG(0, PAR, KK);                                           \
    _Pragma("unroll")                                                              \
    for (int f_ = 0; f_ < 4; ++f_)                                                 \
      RDFRAG(af_[f_], areg_, wm * 128 + (MH) * 64 + f_ * 16 + lr);                 \
    if ((MH) == 0) {                                                               \
      const char* breg_ = REG(1, PAR, KK);                                         \
      _Pragma("unroll")                                                            \
      for (int j_ = 0; j_ < 4; ++j_)                                               \
        RDFRAG(bfr[j_], breg_, wn * 64 + j_ * 16 + lr);                            \
    }                                                                              \
    if (DOSTAGE) STAGE_HALF(S_AB, S_T, S_KK);                                      \
    if ((VM) == 8) asm volatile("s_waitcnt vmcnt(8)" ::: "memory");                \
    if ((VM) == 4) asm volatile("s_waitcnt vmcnt(4)" ::: "memory");                \
    if ((VM) == 0) asm volatile("s_waitcnt vmcnt(0)" ::: "memory");                \
    __builtin_amdgcn_sched_barrier(0);                                             \
    __builtin_amdgcn_s_barrier();                                                  \
    asm volatile("s_waitcnt lgkmcnt(0)" ::: "memory");                             \
    __builtin_amdgcn_sched_barrier(0);                                             \
    __builtin_amdgcn_s_setprio(1);                                                 \
    _Pragma("unroll")                                                              \
    for (int f_ = 0; f_ < 4; ++f_)                                                 \
      _Pragma("unroll")                                                            \
      for (int j_ = 0; j_ < 4; ++j_)                                               \
        acc[(MH) * 4 + f_][j_] = __builtin_amdgcn_mfma_f32_16x16x32_bf16(          \
            af_[f_], bfr[j_], acc[(MH) * 4 + f_][j_], 0, 0, 0);                    \
    __builtin_amdgcn_s_setprio(0);                                                 \
    __builtin_amdgcn_s_barrier();                                                  \
  }

  STAGE_HALF(0, 0, 0); STAGE_HALF(1, 0, 0);
  STAGE_HALF(0, 0, 1); STAGE_HALF(1, 0, 1);
  STAGE_HALF(0, 1, 0); STAGE_HALF(1, 1, 0);
  asm volatile("s_waitcnt vmcnt(4)" ::: "memory");
  __builtin_amdgcn_sched_barrier(0);
  __builtin_amdgcn_s_barrier();

  for (int i = 0; i < 7; ++i) {
    const int t1 = 2 * i + 1, t2 = 2 * i + 2, t3 = 2 * i + 3;
    PHASE(0, 0, 0, 1, 0, t1, 1, -1);
    PHASE(0, 0, 1, 1, 1, t1, 1,  8);
    PHASE(0, 1, 0, 1, 0, t2, 0, -1);
    PHASE(0, 1, 1, 1, 1, t2, 0,  8);
    PHASE(1, 0, 0, 1, 0, t2, 1, -1);
    PHASE(1, 0, 1, 1, 1, t2, 1,  8);
    PHASE(1, 1, 0, 1, 0, t3, 0, -1);
    PHASE(1, 1, 1, 1, 1, t3, 0,  8);
  }
  PHASE(0, 0, 0, 1, 0, 15, 1, -1);
  PHASE(0, 0, 1, 1, 1, 15, 1,  8);
  PHASE(0, 1, 0, 0, 0, 0, 0, -1);
  PHASE(0, 1, 1, 0, 0, 0, 0,  4);
  PHASE(1, 0, 0, 0, 0, 0, 0, -1);
  PHASE(1, 0, 1, 0, 0, 0, 0,  0);
  PHASE(1, 1, 0, 0, 0, 0, 0, -1);
  PHASE(1, 1, 1, 0, 0, 0, 0, -1);

#undef PHASE
#undef RDFRAG
#undef STAGE_HALF
#undef REG

  if (proj < 2) {
    bf16* outb = proj ? outk : outq;
#pragma unroll
    for (int j = 0; j < 4; ++j) {
      int nl = n0l + wn * 64 + j * 16 + lr;
      int h = nl >> 6, d = nl & 63;
      int i2 = d >> 1;
      bool odd = d & 1;
#pragma unroll
      for (int i = 0; i < 8; ++i) {
#pragma unroll
        for (int rr = 0; rr < 4; ++rr) {
          int m = m0 + wm * 128 + i * 16 + lg * 4 + rr;
          float v = acc[i][j][rr];
          float o = __shfl_xor(v, 1);
          float2 cs = tab[(m << 5) + i2];
          float res = odd ? (v * cs.x + o * cs.y) : (v * cs.x - o * cs.y);
          if (proj == 0) res *= 0.125f * 1.44269504f;   // 1/sqrt(hd) * log2(e)
          outb[((size_t)((m >> 11) * NH + h) * SEQ + (m & 2047)) * HD + d] = (bf16)res;
        }
      }
    }
  } else {
#pragma unroll
    for (int j = 0; j < 4; ++j) {
      int nl = n0l + wn * 64 + j * 16 + lr;
      int h = nl >> 6, d = nl & 63;
#pragma unroll
      for (int i = 0; i < 8; ++i) {
#pragma unroll
        for (int rr = 0; rr < 4; ++rr) {
          int m = m0 + wm * 128 + i * 16 + lg * 4 + rr;
          outv[((size_t)((m >> 11) * NH + h) * HD + d) * SEQ + (m & 2047)] = (bf16)acc[i][j][rr];
        }
      }
    }
  }
}

// ---------------- output projection GEMM: single-barrier ring (frozen r15) ----------------
__global__ __launch_bounds__(256) void gemm_out(
    const bf16* __restrict__ A, const bf16* __restrict__ Bw, float* __restrict__ outf)
{
  __shared__ bf16 As[2][128 * 32];
  __shared__ bf16 Bs[2][128 * 32];
  const int t = threadIdx.x;
  const int w = t >> 6;
  const int lane = t & 63;
  const int lr = lane & 15;
  const int lg = lane >> 4;
  const int m0 = blockIdx.y * 128;
  const int n0 = blockIdx.x * 128;
  const int wr = w >> 1, wc = w & 1;
  const char* Bb = (const char*)Bw;

  f32x4 acc[4][4] = {};

#define STAGE_OUT(KT, SLOT)                                                            \
  {                                                                                    \
    _Pragma("unroll")                                                                  \
    for (int p = 0; p < 2; ++p) {                                                      \
      int o = (p * 256 + t) * 16;                                                      \
      int r = o >> 6, cb = o & 63;                                                     \
      int m = m0 + r;                                                                  \
      const char* ga = (const char*)A +                                                \
          ((((size_t)(m >> 11) * NH + ((KT) >> 1)) * SEQ + (m & 2047)) * HD +          \
           ((KT) & 1) * 32) * 2 + cb;                                                  \
      gload_lds16(ga, (char*)As[SLOT] + o);                                            \
    }                                                                                  \
    _Pragma("unroll")                                                                  \
    for (int p = 0; p < 2; ++p) {                                                      \
      int o = (p * 256 + t) * 16;                                                      \
      int r = o >> 6, cb = o & 63;                                                     \
      gload_lds16(Bb + (size_t)(n0 + r) * 2048 + (KT) * 64 + cb, (char*)Bs[SLOT] + o); \
    }                                                                                  \
  }

  STAGE_OUT(0, 0);
  for (int kt = 0; kt < 32; ++kt) {
    asm volatile("s_waitcnt vmcnt(0)" ::: "memory");
    __builtin_amdgcn_sched_barrier(0);
    __builtin_amdgcn_s_barrier();
    if (kt + 1 < 32) STAGE_OUT(kt + 1, (kt + 1) & 1);

    const bf16* Abuf = As[kt & 1];
    const bf16* Bbuf = Bs[kt & 1];
    bf16x8 af[4], bfr[4];
#pragma unroll
    for (int f = 0; f < 4; ++f) {
      af[f]  = *reinterpret_cast<const bf16x8*>(Abuf + (wr * 64 + f * 16 + lr) * 32 + lg * 8);
      bfr[f] = *reinterpret_cast<const bf16x8*>(Bbuf + (wc * 64 + f * 16 + lr) * 32 + lg * 8);
    }
    __builtin_amdgcn_s_setprio(1);
#pragma unroll
    for (int i = 0; i < 4; ++i)
#pragma unroll
      for (int j = 0; j < 4; ++j)
        acc[i][j] = __builtin_amdgcn_mfma_f32_16x16x32_bf16(af[i], bfr[j], acc[i][j], 0, 0, 0);
    __builtin_amdgcn_s_setprio(0);
  }

#pragma unroll
  for (int j = 0; j < 4; ++j) {
    int n = n0 + wc * 64 + j * 16 + lr;
#pragma unroll
    for (int i = 0; i < 4; ++i) {
#pragma unroll
      for (int rr = 0; rr < 4; ++rr) {
        int m = m0 + wr * 64 + i * 16 + lg * 4 + rr;
        outf[(size_t)m * DM + n] = acc[i][j][rr];
      }
    }
  }
#undef STAGE_OUT
}

// ---------------- flash attention: split-KV balanced blocks ----------------
// 768 blocks x 512 threads, heavy-first order. j<=7: direct (final write).
// j>=8: two chunk blocks (pairs [0,h0) / [h0,j+1), h0=(j+1)/2), each writes
// unnormalized partials (acc bf16, m/l f32); attn_merge combines them.
__device__ __forceinline__ void stage512(const char* gRow0, size_t rowStrideB, int colByte0,
                                         char* lds, int t) {
  int o = t * 16;
  int r = o >> 7;
  int cb = o & 127;
  int cbs = cb ^ ((r & 7) << 4);
  gload_lds16(gRow0 + (size_t)r * rowStrideB + colByte0 + cbs, lds + o);
}

__device__ __forceinline__ bf16x8 frag64(const char* tile, int row, int colByte) {
  int b = row * 128 + (colByte ^ ((row & 7) << 4));
  return *reinterpret_cast<const bf16x8*>(tile + b);
}

__device__ __forceinline__ unsigned packw(float a, float b) {
  unsigned short la = __builtin_bit_cast(unsigned short, (bf16)a);
  unsigned short lb = __builtin_bit_cast(unsigned short, (bf16)b);
  return (unsigned)la | ((unsigned)lb << 16);
}

// v_permlane32_swap_b32: newA=(A_lo,B_lo), newB=(A_hi,B_hi).
// ONLY call with distinct-valued a,b (identical values risk register coalescing — r10 bug).
__device__ __forceinline__ void plswap(unsigned& a, unsigned& b) {
  asm volatile("v_permlane32_swap_b32 %0, %1" : "+v"(a), "+v"(b));
}

__device__ __forceinline__ void tile_step(const char* Kt, const char* Vt,
                                          const bf16x8* qf,
                                          f32x16& acc0, f32x16& acc1,
                                          float& mrow, float& lrow,
                                          int l31, int h, bool domask, int qloc) {
  f32x16 s0 = {}, s1 = {};
  __builtin_amdgcn_s_setprio(1);
#pragma unroll
  for (int s = 0; s < 4; ++s) {
    bf16x8 kf0 = frag64(Kt, l31, s * 32 + h * 16);
    bf16x8 kf1 = frag64(Kt, 32 + l31, s * 32 + h * 16);
    s0 = __builtin_amdgcn_mfma_f32_32x32x16_bf16(kf0, qf[s], s0, 0, 0, 0);
    s1 = __builtin_amdgcn_mfma_f32_32x32x16_bf16(kf1, qf[s], s1, 0, 0, 0);
  }
  __builtin_amdgcn_s_setprio(0);
  if (domask) {
#pragma unroll
    for (int reg = 0; reg < 16; ++reg) {
      int ro = (reg & 3) + 8 * (reg >> 2) + 4 * h;
      if (ro > qloc) s0[reg] = -1e30f;
      if (ro + 32 > qloc) s1[reg] = -1e30f;
    }
  }
  // ---- row max: nested triples (v_max3-friendly) ----
  float tm[16];
#pragma unroll
  for (int i = 0; i < 16; ++i) tm[i] = fmaxf(s0[i], s1[i]);
  float a0 = fmaxf(fmaxf(tm[0], tm[1]), tm[2]);
  float a1 = fmaxf(fmaxf(tm[3], tm[4]), tm[5]);
  float a2 = fmaxf(fmaxf(tm[6], tm[7]), tm[8]);
  float a3 = fmaxf(fmaxf(tm[9], tm[10]), tm[11]);
  float a4 = fmaxf(fmaxf(tm[12], tm[13]), tm[14]);
  float b0 = fmaxf(fmaxf(a0, a1), a2);
  float b1 = fmaxf(fmaxf(a3, a4), tm[15]);
  float tmax = fmaxf(b0, b1);
  float rmax = fmaxf(tmax, __shfl_xor(tmax, 32));

  bool need = __any(rmax > mrow + 11.5f);   // defer-max (T13), log2 domain
  if (need) {
    float mnew = fmaxf(mrow, rmax);
    float osc = exp2f(mrow - mnew);
#pragma unroll
    for (int reg = 0; reg < 16; ++reg) {
      int rs = (reg & 3) + 8 * (reg >> 2) + 4 * h;
      float o = __shfl(osc, rs);
      acc0[reg] *= o;
      acc1[reg] *= o;
    }
    lrow *= osc;
    mrow = mnew;
  }
#pragma unroll
  for (int i = 0; i < 16; ++i) {
    s0[i] = exp2f(s0[i] - mrow);
    s1[i] = exp2f(s1[i] - mrow);
  }
  // ---- row sum: packed-f32 tree ----
  {
    const f32x2* p0 = reinterpret_cast<const f32x2*>(&s0);
    const f32x2* p1 = reinterpret_cast<const f32x2*>(&s1);
    f32x2 tp[8];
#pragma unroll
    for (int i = 0; i < 8; ++i) tp[i] = p0[i] + p1[i];
    tp[0] += tp[4]; tp[1] += tp[5]; tp[2] += tp[6]; tp[3] += tp[7];
    tp[0] += tp[2]; tp[1] += tp[3];
    tp[0] += tp[1];
    float rs = tp[0][0] + tp[0][1];
    lrow += rs + __shfl_xor(rs, 32);
  }

  // ---- P -> A-fragment repack via permlane32_swap (proven r11) ----
  unsigned W0[4][2], W1[4][2];
#pragma unroll
  for (int sp = 0; sp < 4; ++sp)
#pragma unroll
    for (int u = 0; u < 2; ++u) {
      W0[sp][u] = packw(s0[sp * 4 + 2 * u], s0[sp * 4 + 2 * u + 1]);
      W1[sp][u] = packw(s1[sp * 4 + 2 * u], s1[sp * 4 + 2 * u + 1]);
    }
  __builtin_amdgcn_s_setprio(1);
#pragma unroll
  for (int ks = 0; ks < 4; ++ks) {
    const unsigned (*W)[2] = (ks < 2) ? W0 : W1;
    const int c = ks & 1;
    unsigned a0w = W[2 * c][0], b0w = W[2 * c + 1][0];
    unsigned a1w = W[2 * c][1], b1w = W[2 * c + 1][1];
    plswap(a0w, b0w);
    plswap(a1w, b1w);
    u32x4 pw = {a0w, a1w, b0w, b1w};
    bf16x8 pf = __builtin_bit_cast(bf16x8, pw);
    bf16x8 vf0 = frag64(Vt, l31, ks * 32 + h * 16);
    bf16x8 vf1 = frag64(Vt, 32 + l31, ks * 32 + h * 16);
    acc0 = __builtin_amdgcn_mfma_f32_32x32x16_bf16(pf, vf0, acc0, 0, 0, 0);
    acc1 = __builtin_amdgcn_mfma_f32_32x32x16_bf16(pf, vf1, acc1, 0, 0, 0);
  }
  __builtin_amdgcn_s_setprio(0);
}

__global__ __launch_bounds__(512, 4) void attn_kernel(
    const bf16* __restrict__ q, const bf16* __restrict__ k,
    const bf16* __restrict__ vt, bf16* __restrict__ att,
    bf16* __restrict__ accP, float* __restrict__ mP, float* __restrict__ lP)
{
  __shared__ __align__(16) char pool[65536];
  const int t = threadIdx.x;
  const int w = t >> 6;
  const int wsub = w & 3;
  const int par = w >> 2;
  const int lane = t & 63;
  const int l31 = lane & 31;
  const int h = lane >> 5;

  // decode: 768 blocks = 32 bh x 24 units; heavy units dispatched first.
  const int id = blockIdx.x;
  const int bh = id & 31;
  const int unit = 23 - (id >> 5);
  int j, u0, u1, pidx = 0;
  bool partial;
  if (unit < 8) {
    j = unit; u0 = 0; u1 = j + 1; partial = false;
  } else {
    int v = unit - 8;
    j = 8 + (v >> 1);
    int ch = v & 1;
    int h0 = (j + 1) >> 1;
    u0 = ch ? h0 : 0;
    u1 = ch ? (j + 1) : h0;
    partial = true;
    pidx = (bh * 8 + (j - 8)) * 2 + ch;
  }

  const int strip = 2 * j + (wsub >> 1);
  const int myN = strip + 1;
  const int q0w = j * 128 + wsub * 32;
  const int qloc = (wsub & 1) * 32 + l31;

  const bf16* qb = q + (size_t)bh * SEQ * HD;
  const char* kbB = (const char*)(k + (size_t)bh * SEQ * HD);
  const char* vbB = (const char*)(vt + (size_t)bh * HD * SEQ);

  bf16x8 qf[4];
#pragma unroll
  for (int s = 0; s < 4; ++s)
    qf[s] = *reinterpret_cast<const bf16x8*>(qb + (size_t)(q0w + l31) * HD + s * 16 + h * 8);

  f32x16 acc0 = {}, acc1 = {};
  float mrow = -1e30f, lrow = 0.f;

  // prologue: stage pair u0
  {
    int pt = 2 * u0;
    stage512(kbB + (size_t)pt * 8192, 128, 0, pool + (pt & 3) * 8192, t);
    stage512(vbB, 4096, pt * 128, pool + 32768 + (pt & 3) * 8192, t);
    stage512(kbB + (size_t)(pt + 1) * 8192, 128, 0, pool + ((pt + 1) & 3) * 8192, t);
    stage512(vbB, 4096, (pt + 1) * 128, pool + 32768 + ((pt + 1) & 3) * 8192, t);
  }

  for (int u = u0; u < u1; ++u) {
    asm volatile("s_waitcnt vmcnt(0)" ::: "memory");
    __builtin_amdgcn_sched_barrier(0);
    __builtin_amdgcn_s_barrier();
    if (u + 1 < u1) {
      int nt = 2 * u + 2;
      stage512(kbB + (size_t)nt * 8192, 128, 0, pool + (nt & 3) * 8192, t);
      stage512(vbB, 4096, nt * 128, pool + 32768 + (nt & 3) * 8192, t);
      stage512(kbB + (size_t)(nt + 1) * 8192, 128, 0, pool + ((nt + 1) & 3) * 8192, t);
      stage512(vbB, 4096, (nt + 1) * 128, pool + 32768 + ((nt + 1) & 3) * 8192, t);
    }
    const int tt = 2 * u + par;
    if (tt < myN)
      tile_step(pool + (tt & 3) * 8192, pool + 32768 + (tt & 3) * 8192, qf,
                acc0, acc1, mrow, lrow, l31, h, tt == strip, qloc);
  }

  // all waves must finish reading K/V from pool before the merge overwrites it
  __syncthreads();

  float* mb = (float*)pool;
  float* reg = mb + wsub * (34 * 64);
  if (par == 1) {
#pragma unroll
    for (int i = 0; i < 16; ++i) reg[i * 64 + lane] = acc0[i];
#pragma unroll
    for (int i = 0; i < 16; ++i) reg[(16 + i) * 64 + lane] = acc1[i];
    reg[32 * 64 + lane] = mrow;
    reg[33 * 64 + lane] = lrow;
  }
  __syncthreads();
  if (par == 0) {
    float mB = reg[32 * 64 + lane];
    float lB = reg[33 * 64 + lane];
    float mM = fmaxf(mrow, mB);
    float alpha = exp2f(mrow - mM);
    float beta  = exp2f(mB - mM);
    if (!partial) {
      float linv = 1.0f / (alpha * lrow + beta * lB);
#pragma unroll
      for (int rg = 0; rg < 16; ++rg) {
        int rs = (rg & 3) + 8 * (rg >> 2) + 4 * h;
        float a  = __shfl(alpha, rs);
        float b  = __shfl(beta, rs);
        float li = __shfl(linv, rs);
        float o0 = (a * acc0[rg] + b * reg[rg * 64 + lane]) * li;
        float o1 = (a * acc1[rg] + b * reg[(16 + rg) * 64 + lane]) * li;
        size_t base = ((size_t)bh * SEQ + q0w + rs) * HD;
        att[base + l31]      = (bf16)o0;
        att[base + 32 + l31] = (bf16)o1;
      }
    } else {
      float lC = alpha * lrow + beta * lB;
      if (h == 0) {
        mP[pidx * 128 + wsub * 32 + l31] = mM;
        lP[pidx * 128 + wsub * 32 + l31] = lC;
      }
#pragma unroll
      for (int rg = 0; rg < 16; ++rg) {
        int rs = (rg & 3) + 8 * (rg >> 2) + 4 * h;
        float a = __shfl(alpha, rs);
        float b = __shfl(beta, rs);
        float c0 = a * acc0[rg] + b * reg[rg * 64 + lane];
        float c1 = a * acc1[rg] + b * reg[(16 + rg) * 64 + lane];
        size_t base = (size_t)pidx * 8192 + (size_t)(wsub * 32 + rs) * 64;
        accP[base + l31]      = (bf16)c0;
        accP[base + 32 + l31] = (bf16)c1;
      }
    }
  }
}

// merge the two kv-chunks of each j>=8 strip: O = (e0 a0 + e1 a1) / (e0 l0 + e1 l1)
__global__ __launch_bounds__(256) void attn_merge(
    const bf16* __restrict__ accP, const float* __restrict__ mP,
    const float* __restrict__ lP, bf16* __restrict__ att)
{
  int gid = blockIdx.x * 256 + threadIdx.x;   // 32*8*128*64 = 2M
  int c = gid & 63;
  int r = (gid >> 6) & 127;
  int j8 = (gid >> 13) & 7;
  int bh = gid >> 16;
  int p0 = (bh * 8 + j8) * 2;
  float m0 = mP[p0 * 128 + r], m1 = mP[(p0 + 1) * 128 + r];
  float l0 = lP[p0 * 128 + r], l1 = lP[(p0 + 1) * 128 + r];
  float a0 = (float)accP[(size_t)p0 * 8192 + r * 64 + c];
  float a1 = (float)accP[(size_t)(p0 + 1) * 8192 + r * 64 + c];
  float mM = fmaxf(m0, m1);
  float e0 = exp2f(m0 - mM), e1 = exp2f(m1 - mM);
  float o = (e0 * a0 + e1 * a1) / (e0 * l0 + e1 * l1);
  att[((size_t)bh * SEQ + (8 + j8) * 128 + r) * HD + c] = (bf16)o;
}

extern "C" void kernel_launch(void* const* d_in, const int* in_sizes, int n_in,
                              void* d_out, int out_size, void* d_ws, size_t ws_size,
                              hipStream_t stream) {
  const float* x  = (const float*)d_in[0];
  const int* pos  = (const int*)d_in[1];
  const float* Wq = (const float*)d_in[2];
  const float* Wk = (const float*)d_in[3];
  const float* Wv = (const float*)d_in[4];
  const float* Wo = (const float*)d_in[5];
  float* out = (float*)d_out;

  char* p = (char*)d_ws;
  bf16* xb   = (bf16*)p; p += (size_t)MTOT * DM * 2;
  bf16* wqb  = (bf16*)p; p += (size_t)DM * DM * 2;
  bf16* wkb  = (bf16*)p; p += (size_t)DM * DM * 2;
  bf16* wvb  = (bf16*)p; p += (size_t)DM * DM * 2;
  bf16* wob  = (bf16*)p; p += (size_t)DM * DM * 2;
  bf16* qb   = (bf16*)p; p += (size_t)MTOT * DM * 2;
  bf16* kb   = (bf16*)p; p += (size_t)MTOT * DM * 2;
  bf16* vtb  = (bf16*)p; p += (size_t)MTOT * DM * 2;
  bf16* attb = (bf16*)p; p += (size_t)MTOT * DM * 2;
  float2* tab = (float2*)p; p += (size_t)MTOT * 32 * sizeof(float2);
  (void)wkb; (void)wvb;

  // reuse regions dead after gemm_qkv: xb (8 MB) -> accP (512 chunks x 128 x 64 bf16 = 8 MB);
  // tab (1 MB) -> mP (256 KB) + lP (256 KB).
  bf16* accP = xb;
  float* mP = (float*)tab;
  float* lP = mP + 512 * 128;

  prep_kernel<<<(2097152 + 131072 + 255) / 256, 256, 0, stream>>>(
      x, Wq, Wk, Wv, Wo, pos, xb, wqb, tab);

  gemm_qkv<<<dim3(12, MTOT / 256), 512, 0, stream>>>(xb, wqb, qb, kb, vtb, tab);

  attn_kernel<<<768, 512, 0, stream>>>(qb, kb, vtb, attb, accP, mP, lP);

  attn_merge<<<8192, 256, 0, stream>>>(accP, mP, lP, attb);

  gemm_out<<<dim3(DM / 128, MTOT / 128), 256, 0, stream>>>(attb, wob, out);
}

// Round 17
// 115.943 us; speedup vs baseline: 1.0840x; 1.0840x over previous
//
#include <hip/hip_runtime.h>
#include <hip/hip_bf16.h>

typedef __bf16 bf16;
typedef __bf16 bf16x4 __attribute__((ext_vector_type(4)));
typedef __bf16 bf16x8 __attribute__((ext_vector_type(8)));
typedef float f32x2 __attribute__((ext_vector_type(2)));
typedef float f32x4 __attribute__((ext_vector_type(4)));
typedef float f32x16 __attribute__((ext_vector_type(16)));
typedef unsigned int u32x4 __attribute__((ext_vector_type(4)));

#define NH 16
#define HD 64
#define SEQ 2048
#define DM 1024
#define MTOT 4096   // B*S

__device__ __forceinline__ void gload_lds16(const void* g, void* l) {
  __builtin_amdgcn_global_load_lds(
      (const __attribute__((address_space(1))) void*)g,
      (__attribute__((address_space(3))) void*)l, 16, 0, 0);
}

// ---------------- fused prep: x->bf16, 4 weights->bf16, RoPE table ----------------
__global__ __launch_bounds__(256) void prep_kernel(
    const float* __restrict__ x,
    const float* __restrict__ w0, const float* __restrict__ w1,
    const float* __restrict__ w2, const float* __restrict__ w3,
    const int* __restrict__ pos,
    bf16* __restrict__ xb, bf16* __restrict__ wb, float2* __restrict__ tab)
{
  int i = blockIdx.x * 256 + threadIdx.x;
  if (i < 1048576) {
    float4 v = reinterpret_cast<const float4*>(x)[i];
    bf16x4 o;
    o[0] = (bf16)v.x; o[1] = (bf16)v.y; o[2] = (bf16)v.z; o[3] = (bf16)v.w;
    *reinterpret_cast<bf16x4*>(xb + (size_t)i * 4) = o;
  } else if (i < 2097152) {
    int k = i - 1048576;
    int seg = k >> 18, j = k & 262143;
    const float* src = seg == 0 ? w0 : seg == 1 ? w1 : seg == 2 ? w2 : w3;
    float4 v = reinterpret_cast<const float4*>(src)[j];
    bf16x4 o;
    o[0] = (bf16)v.x; o[1] = (bf16)v.y; o[2] = (bf16)v.z; o[3] = (bf16)v.w;
    *reinterpret_cast<bf16x4*>(wb + ((size_t)seg << 20) + (size_t)j * 4) = o;
  } else if (i < 2097152 + 131072) {
    int k = i - 2097152;
    int m = k >> 5, i2 = k & 31;
    float pf = (float)pos[m];
    float inv = 1.0f / powf(10000.0f, (float)(2 * i2) * (1.0f / 64.0f));
    float a = pf * inv;
    tab[k] = make_float2(cosf(a), sinf(a));
  }
}

// ---------------- fused QKV projection GEMM, 256x256 tile, BK=64, 8-PHASE ----------------
// (frozen — verified r9/r11) grid (12, 16): proj = x>>2, n0 = (x&3)*256.
__global__ __launch_bounds__(512, 2) void gemm_qkv(
    const bf16* __restrict__ A, const bf16* __restrict__ wAll,
    bf16* __restrict__ outq, bf16* __restrict__ outk, bf16* __restrict__ outv,
    const float2* __restrict__ tab)
{
  __shared__ bf16 ABlds[2][2][2][8192];   // [A=0/B=1][parity][kk] 256x32 bf16 = 16 KB
  const int t = threadIdx.x;
  const int w = t >> 6;
  const int wm = w >> 2, wn = w & 3;
  const int lane = t & 63;
  const int lr = lane & 15;
  const int lg = lane >> 4;
  const int m0 = blockIdx.y * 256;
  const int proj = blockIdx.x >> 2;
  const int n0l = (blockIdx.x & 3) * 256;
  const char* Asrc = (const char*)A + (size_t)m0 * 2048;
  const char* Bsrc = (const char*)(wAll + ((size_t)proj << 20) + (size_t)n0l * DM);

  f32x4 acc[8][4] = {};
  bf16x8 bfr[4];

#define REG(AB_, PAR_, KK_) ((char*)ABlds + (((AB_)*4 + (PAR_)*2 + (KK_)) * 16384))

#define STAGE_HALF(AB_, T_, KK_)                                                   \
  {                                                                                \
    const char* gb_ = (AB_) ? Bsrc : Asrc;                                         \
    char* lb_ = REG(AB_, (T_) & 1, KK_);                                           \
    _Pragma("unroll")                                                              \
    for (int p_ = 0; p_ < 2; ++p_) {                                               \
      int o_ = (p_ * 512 + t) * 16;                                                \
      int r_ = o_ >> 6, c_ = o_ & 63;                                              \
      int cs_ = c_ ^ (((r_ >> 1) & 3) << 4);                                       \
      gload_lds16(gb_ + (size_t)r_ * 2048 + (T_) * 128 + (KK_) * 64 + cs_,         \
                  lb_ + o_);                                                       \
    }                                                                              \
  }

#define RDFRAG(DST, REGP, ROW)                                                     \
  {                                                                                \
    int row_ = (ROW);                                                              \
    int cb_ = (lg * 16) ^ (((row_ >> 1) & 3) << 4);                                \
    DST = *reinterpret_cast<const bf16x8*>((REGP) + row_ * 64 + cb_);              \
  }

#define PHASE(PAR, KK, MH, DOSTAGE, S_AB, S_T, S_KK, VM)                           \
  {                                                                                \
    bf16x8 af_[4];                                                                 \
    const char* areg_ = REG(0, PAR, KK);                                           \
    _Pragma("unroll")                                                              \
    for (int f_ = 0; f_ < 4; ++f_)                                                 \
      RDFRAG(af_[f_], areg_, wm * 128 + (MH) * 64 + f_ * 16 + lr);                 \
    if ((MH) == 0) {                                                               \
      const char* breg_ = REG(1, PAR, KK);                                         \
      _Pragma("unroll")                                                            \
      for (int j_ = 0; j_ < 4; ++j_)                                               \
        RDFRAG(bfr[j_], breg_, wn * 64 + j_ * 16 + lr);                            \
    }                                                                              \
    if (DOSTAGE) STAGE_HALF(S_AB, S_T, S_KK);                                      \
    if ((VM) == 8) asm volatile("s_waitcnt vmcnt(8)" ::: "memory");                \
    if ((VM) == 4) asm volatile("s_waitcnt vmcnt(4)" ::: "memory");                \
    if ((VM) == 0) asm volatile("s_waitcnt vmcnt(0)" ::: "memory");                \
    __builtin_amdgcn_sched_barrier(0);                                             \
    __builtin_amdgcn_s_barrier();                                                  \
    asm volatile("s_waitcnt lgkmcnt(0)" ::: "memory");                             \
    __builtin_amdgcn_sched_barrier(0);                                             \
    __builtin_amdgcn_s_setprio(1);                                                 \
    _Pragma("unroll")                                                              \
    for (int f_ = 0; f_ < 4; ++f_)                                                 \
      _Pragma("unroll")                                                            \
      for (int j_ = 0; j_ < 4; ++j_)                                               \
        acc[(MH) * 4 + f_][j_] = __builtin_amdgcn_mfma_f32_16x16x32_bf16(          \
            af_[f_], bfr[j_], acc[(MH) * 4 + f_][j_], 0, 0, 0);                    \
    __builtin_amdgcn_s_setprio(0);                                                 \
    __builtin_amdgcn_s_barrier();                                                  \
  }

  STAGE_HALF(0, 0, 0); STAGE_HALF(1, 0, 0);
  STAGE_HALF(0, 0, 1); STAGE_HALF(1, 0, 1);
  STAGE_HALF(0, 1, 0); STAGE_HALF(1, 1, 0);
  asm volatile("s_waitcnt vmcnt(4)" ::: "memory");
  __builtin_amdgcn_sched_barrier(0);
  __builtin_amdgcn_s_barrier();

  for (int i = 0; i < 7; ++i) {
    const int t1 = 2 * i + 1, t2 = 2 * i + 2, t3 = 2 * i + 3;
    PHASE(0, 0, 0, 1, 0, t1, 1, -1);
    PHASE(0, 0, 1, 1, 1, t1, 1,  8);
    PHASE(0, 1, 0, 1, 0, t2, 0, -1);
    PHASE(0, 1, 1, 1, 1, t2, 0,  8);
    PHASE(1, 0, 0, 1, 0, t2, 1, -1);
    PHASE(1, 0, 1, 1, 1, t2, 1,  8);
    PHASE(1, 1, 0, 1, 0, t3, 0, -1);
    PHASE(1, 1, 1, 1, 1, t3, 0,  8);
  }
  PHASE(0, 0, 0, 1, 0, 15, 1, -1);
  PHASE(0, 0, 1, 1, 1, 15, 1,  8);
  PHASE(0, 1, 0, 0, 0, 0, 0, -1);
  PHASE(0, 1, 1, 0, 0, 0, 0,  4);
  PHASE(1, 0, 0, 0, 0, 0, 0, -1);
  PHASE(1, 0, 1, 0, 0, 0, 0,  0);
  PHASE(1, 1, 0, 0, 0, 0, 0, -1);
  PHASE(1, 1, 1, 0, 0, 0, 0, -1);

#undef PHASE
#undef RDFRAG
#undef STAGE_HALF
#undef REG

  if (proj < 2) {
    bf16* outb = proj ? outk : outq;
#pragma unroll
    for (int j = 0; j < 4; ++j) {
      int nl = n0l + wn * 64 + j * 16 + lr;
      int h = nl >> 6, d = nl & 63;
      int i2 = d >> 1;
      bool odd = d & 1;
#pragma unroll
      for (int i = 0; i < 8; ++i) {
#pragma unroll
        for (int rr = 0; rr < 4; ++rr) {
          int m = m0 + wm * 128 + i * 16 + lg * 4 + rr;
          float v = acc[i][j][rr];
          float o = __shfl_xor(v, 1);
          float2 cs = tab[(m << 5) + i2];
          float res = odd ? (v * cs.x + o * cs.y) : (v * cs.x - o * cs.y);
          if (proj == 0) res *= 0.125f * 1.44269504f;   // 1/sqrt(hd) * log2(e)
          outb[((size_t)((m >> 11) * NH + h) * SEQ + (m & 2047)) * HD + d] = (bf16)res;
        }
      }
    }
  } else {
#pragma unroll
    for (int j = 0; j < 4; ++j) {
      int nl = n0l + wn * 64 + j * 16 + lr;
      int h = nl >> 6, d = nl & 63;
#pragma unroll
      for (int i = 0; i < 8; ++i) {
#pragma unroll
        for (int rr = 0; rr < 4; ++rr) {
          int m = m0 + wm * 128 + i * 16 + lg * 4 + rr;
          outv[((size_t)((m >> 11) * NH + h) * HD + d) * SEQ + (m & 2047)] = (bf16)acc[i][j][rr];
        }
      }
    }
  }
}

// ---------------- output projection GEMM: 128x64 tile, 512 blocks (2/CU) ----------------
// single-barrier ring; 4 waves (2M x 2N), per-wave C = 64x32 (acc[4][2]).
__global__ __launch_bounds__(256) void gemm_out(
    const bf16* __restrict__ A, const bf16* __restrict__ Bw, float* __restrict__ outf)
{
  __shared__ bf16 As[2][128 * 32];
  __shared__ bf16 Bs[2][64 * 32];
  const int t = threadIdx.x;
  const int w = t >> 6;
  const int lane = t & 63;
  const int lr = lane & 15;
  const int lg = lane >> 4;
  const int m0 = blockIdx.y * 128;
  const int n0 = blockIdx.x * 64;
  const int wr = w >> 1, wc = w & 1;
  const char* Bb = (const char*)Bw;

  f32x4 acc[4][2] = {};

#define STAGE_OUT(KT, SLOT)                                                            \
  {                                                                                    \
    _Pragma("unroll")                                                                  \
    for (int p = 0; p < 2; ++p) {                                                      \
      int o = (p * 256 + t) * 16;                                                      \
      int r = o >> 6, cb = o & 63;                                                     \
      int m = m0 + r;                                                                  \
      const char* ga = (const char*)A +                                                \
          ((((size_t)(m >> 11) * NH + ((KT) >> 1)) * SEQ + (m & 2047)) * HD +          \
           ((KT) & 1) * 32) * 2 + cb;                                                  \
      gload_lds16(ga, (char*)As[SLOT] + o);                                            \
    }                                                                                  \
    {                                                                                  \
      int o = t * 16;                                                                  \
      int r = o >> 6, cb = o & 63;                                                     \
      gload_lds16(Bb + (size_t)(n0 + r) * 2048 + (KT) * 64 + cb, (char*)Bs[SLOT] + o); \
    }                                                                                  \
  }

  STAGE_OUT(0, 0);
  for (int kt = 0; kt < 32; ++kt) {
    asm volatile("s_waitcnt vmcnt(0)" ::: "memory");
    __builtin_amdgcn_sched_barrier(0);
    __builtin_amdgcn_s_barrier();
    if (kt + 1 < 32) STAGE_OUT(kt + 1, (kt + 1) & 1);

    const bf16* Abuf = As[kt & 1];
    const bf16* Bbuf = Bs[kt & 1];
    bf16x8 af[4], bfr[2];
#pragma unroll
    for (int f = 0; f < 4; ++f)
      af[f] = *reinterpret_cast<const bf16x8*>(Abuf + (wr * 64 + f * 16 + lr) * 32 + lg * 8);
#pragma unroll
    for (int f = 0; f < 2; ++f)
      bfr[f] = *reinterpret_cast<const bf16x8*>(Bbuf + (wc * 32 + f * 16 + lr) * 32 + lg * 8);
    __builtin_amdgcn_s_setprio(1);
#pragma unroll
    for (int i = 0; i < 4; ++i)
#pragma unroll
      for (int j = 0; j < 2; ++j)
        acc[i][j] = __builtin_amdgcn_mfma_f32_16x16x32_bf16(af[i], bfr[j], acc[i][j], 0, 0, 0);
    __builtin_amdgcn_s_setprio(0);
  }

#pragma unroll
  for (int j = 0; j < 2; ++j) {
    int n = n0 + wc * 32 + j * 16 + lr;
#pragma unroll
    for (int i = 0; i < 4; ++i) {
#pragma unroll
      for (int rr = 0; rr < 4; ++rr) {
        int m = m0 + wr * 64 + i * 16 + lg * 4 + rr;
        outf[(size_t)m * DM + n] = acc[i][j][rr];
      }
    }
  }
#undef STAGE_OUT
}

// ---------------- flash attention (r15-proven: single-barrier pair ring) ----------------
__device__ __forceinline__ void stage512(const char* gRow0, size_t rowStrideB, int colByte0,
                                         char* lds, int t) {
  int o = t * 16;
  int r = o >> 7;
  int cb = o & 127;
  int cbs = cb ^ ((r & 7) << 4);
  gload_lds16(gRow0 + (size_t)r * rowStrideB + colByte0 + cbs, lds + o);
}

__device__ __forceinline__ bf16x8 frag64(const char* tile, int row, int colByte) {
  int b = row * 128 + (colByte ^ ((row & 7) << 4));
  return *reinterpret_cast<const bf16x8*>(tile + b);
}

__device__ __forceinline__ unsigned packw(float a, float b) {
  unsigned short la = __builtin_bit_cast(unsigned short, (bf16)a);
  unsigned short lb = __builtin_bit_cast(unsigned short, (bf16)b);
  return (unsigned)la | ((unsigned)lb << 16);
}

// v_permlane32_swap_b32: newA=(A_lo,B_lo), newB=(A_hi,B_hi).
// ONLY call with distinct-valued a,b (identical values risk register coalescing — r10 bug).
__device__ __forceinline__ void plswap(unsigned& a, unsigned& b) {
  asm volatile("v_permlane32_swap_b32 %0, %1" : "+v"(a), "+v"(b));
}

__device__ __forceinline__ void tile_step(const char* Kt, const char* Vt,
                                          const bf16x8* qf,
                                          f32x16& acc0, f32x16& acc1,
                                          float& mrow, float& lrow,
                                          int l31, int h, bool domask, int qloc) {
  f32x16 s0 = {}, s1 = {};
  __builtin_amdgcn_s_setprio(1);
#pragma unroll
  for (int s = 0; s < 4; ++s) {
    bf16x8 kf0 = frag64(Kt, l31, s * 32 + h * 16);
    bf16x8 kf1 = frag64(Kt, 32 + l31, s * 32 + h * 16);
    s0 = __builtin_amdgcn_mfma_f32_32x32x16_bf16(kf0, qf[s], s0, 0, 0, 0);
    s1 = __builtin_amdgcn_mfma_f32_32x32x16_bf16(kf1, qf[s], s1, 0, 0, 0);
  }
  __builtin_amdgcn_s_setprio(0);
  if (domask) {
#pragma unroll
    for (int reg = 0; reg < 16; ++reg) {
      int ro = (reg & 3) + 8 * (reg >> 2) + 4 * h;
      if (ro > qloc) s0[reg] = -1e30f;
      if (ro + 32 > qloc) s1[reg] = -1e30f;
    }
  }
  // ---- row max: nested triples (v_max3-friendly) ----
  float tm[16];
#pragma unroll
  for (int i = 0; i < 16; ++i) tm[i] = fmaxf(s0[i], s1[i]);
  float a0 = fmaxf(fmaxf(tm[0], tm[1]), tm[2]);
  float a1 = fmaxf(fmaxf(tm[3], tm[4]), tm[5]);
  float a2 = fmaxf(fmaxf(tm[6], tm[7]), tm[8]);
  float a3 = fmaxf(fmaxf(tm[9], tm[10]), tm[11]);
  float a4 = fmaxf(fmaxf(tm[12], tm[13]), tm[14]);
  float b0 = fmaxf(fmaxf(a0, a1), a2);
  float b1 = fmaxf(fmaxf(a3, a4), tm[15]);
  float tmax = fmaxf(b0, b1);
  float rmax = fmaxf(tmax, __shfl_xor(tmax, 32));

  bool need = __any(rmax > mrow + 11.5f);   // defer-max (T13), log2 domain
  if (need) {
    float mnew = fmaxf(mrow, rmax);
    float osc = exp2f(mrow - mnew);
#pragma unroll
    for (int reg = 0; reg < 16; ++reg) {
      int rs = (reg & 3) + 8 * (reg >> 2) + 4 * h;
      float o = __shfl(osc, rs);
      acc0[reg] *= o;
      acc1[reg] *= o;
    }
    lrow *= osc;
    mrow = mnew;
  }
#pragma unroll
  for (int i = 0; i < 16; ++i) {
    s0[i] = exp2f(s0[i] - mrow);
    s1[i] = exp2f(s1[i] - mrow);
  }
  // ---- row sum: packed-f32 tree ----
  {
    const f32x2* p0 = reinterpret_cast<const f32x2*>(&s0);
    const f32x2* p1 = reinterpret_cast<const f32x2*>(&s1);
    f32x2 tp[8];
#pragma unroll
    for (int i = 0; i < 8; ++i) tp[i] = p0[i] + p1[i];
    tp[0] += tp[4]; tp[1] += tp[5]; tp[2] += tp[6]; tp[3] += tp[7];
    tp[0] += tp[2]; tp[1] += tp[3];
    tp[0] += tp[1];
    float rs = tp[0][0] + tp[0][1];
    lrow += rs + __shfl_xor(rs, 32);
  }

  // ---- P -> A-fragment repack via permlane32_swap (proven r11) ----
  unsigned W0[4][2], W1[4][2];
#pragma unroll
  for (int sp = 0; sp < 4; ++sp)
#pragma unroll
    for (int u = 0; u < 2; ++u) {
      W0[sp][u] = packw(s0[sp * 4 + 2 * u], s0[sp * 4 + 2 * u + 1]);
      W1[sp][u] = packw(s1[sp * 4 + 2 * u], s1[sp * 4 + 2 * u + 1]);
    }
  __builtin_amdgcn_s_setprio(1);
#pragma unroll
  for (int ks = 0; ks < 4; ++ks) {
    const unsigned (*W)[2] = (ks < 2) ? W0 : W1;
    const int c = ks & 1;
    unsigned a0w = W[2 * c][0], b0w = W[2 * c + 1][0];
    unsigned a1w = W[2 * c][1], b1w = W[2 * c + 1][1];
    plswap(a0w, b0w);
    plswap(a1w, b1w);
    u32x4 pw = {a0w, a1w, b0w, b1w};
    bf16x8 pf = __builtin_bit_cast(bf16x8, pw);
    bf16x8 vf0 = frag64(Vt, l31, ks * 32 + h * 16);
    bf16x8 vf1 = frag64(Vt, 32 + l31, ks * 32 + h * 16);
    acc0 = __builtin_amdgcn_mfma_f32_32x32x16_bf16(pf, vf0, acc0, 0, 0, 0);
    acc1 = __builtin_amdgcn_mfma_f32_32x32x16_bf16(pf, vf1, acc1, 0, 0, 0);
  }
  __builtin_amdgcn_s_setprio(0);
}

__global__ __launch_bounds__(512, 4) void attn_kernel(
    const bf16* __restrict__ q, const bf16* __restrict__ k,
    const bf16* __restrict__ vt, bf16* __restrict__ att)
{
  __shared__ __align__(16) char pool[65536];
  const int t = threadIdx.x;
  const int w = t >> 6;
  const int wsub = w & 3;
  const int par = w >> 2;
  const int lane = t & 63;
  const int l31 = lane & 31;
  const int h = lane >> 5;

  // XCD-local bh mapping (r14): all 16 blocks of a bh on one XCD; complementary pairing kept.
  const int id = blockIdx.x;
  const int bh = (id & 7) + 8 * ((id >> 3) & 3);
  const int rem = id >> 5;           // 0..15
  const int halfb = rem >> 3;        // 0/1
  const int jj = rem & 7;
  const int j = halfb ? jj : 15 - jj;

  const int strip = 2 * j + (wsub >> 1);
  const int myN = strip + 1;
  const int npair = j + 1;
  const int q0w = j * 128 + wsub * 32;
  const int qloc = (wsub & 1) * 32 + l31;

  const bf16* qb = q + (size_t)bh * SEQ * HD;
  const char* kbB = (const char*)(k + (size_t)bh * SEQ * HD);
  const char* vbB = (const char*)(vt + (size_t)bh * HD * SEQ);

  bf16x8 qf[4];
#pragma unroll
  for (int s = 0; s < 4; ++s)
    qf[s] = *reinterpret_cast<const bf16x8*>(qb + (size_t)(q0w + l31) * HD + s * 16 + h * 8);

  f32x16 acc0 = {}, acc1 = {};
  float mrow = -1e30f, lrow = 0.f;

  // prologue: stage pair 0 (tiles 0,1)
  stage512(kbB, 128, 0, pool + 0 * 8192, t);
  stage512(vbB, 4096, 0, pool + 32768 + 0 * 8192, t);
  stage512(kbB + 8192, 128, 0, pool + 1 * 8192, t);
  stage512(vbB, 4096, 128, pool + 32768 + 1 * 8192, t);

  for (int u = 0; u < npair; ++u) {
    asm volatile("s_waitcnt vmcnt(0)" ::: "memory");
    __builtin_amdgcn_sched_barrier(0);
    __builtin_amdgcn_s_barrier();
    if (u + 1 < npair) {
      int nt = 2 * u + 2;
      stage512(kbB + (size_t)nt * 8192, 128, 0, pool + (nt & 3) * 8192, t);
      stage512(vbB, 4096, nt * 128, pool + 32768 + (nt & 3) * 8192, t);
      stage512(kbB + (size_t)(nt + 1) * 8192, 128, 0, pool + ((nt + 1) & 3) * 8192, t);
      stage512(vbB, 4096, (nt + 1) * 128, pool + 32768 + ((nt + 1) & 3) * 8192, t);
    }
    const int tt = 2 * u + par;
    if (tt < myN)
      tile_step(pool + (tt & 3) * 8192, pool + 32768 + (tt & 3) * 8192, qf,
                acc0, acc1, mrow, lrow, l31, h, tt == strip, qloc);
  }

  // all waves must finish reading K/V from pool before the merge overwrites it
  __syncthreads();

  float* mb = (float*)pool;
  float* reg = mb + wsub * (34 * 64);
  if (par == 1) {
#pragma unroll
    for (int i = 0; i < 16; ++i) reg[i * 64 + lane] = acc0[i];
#pragma unroll
    for (int i = 0; i < 16; ++i) reg[(16 + i) * 64 + lane] = acc1[i];
    reg[32 * 64 + lane] = mrow;
    reg[33 * 64 + lane] = lrow;
  }
  __syncthreads();
  if (par == 0) {
    float mB = reg[32 * 64 + lane];
    float lB = reg[33 * 64 + lane];
    float mM = fmaxf(mrow, mB);
    float alpha = exp2f(mrow - mM);
    float beta  = exp2f(mB - mM);
    float linv = 1.0f / (alpha * lrow + beta * lB);
#pragma unroll
    for (int rg = 0; rg < 16; ++rg) {
      int rs = (rg & 3) + 8 * (rg >> 2) + 4 * h;
      float a  = __shfl(alpha, rs);
      float b  = __shfl(beta, rs);
      float li = __shfl(linv, rs);
      float o0 = (a * acc0[rg] + b * reg[rg * 64 + lane]) * li;
      float o1 = (a * acc1[rg] + b * reg[(16 + rg) * 64 + lane]) * li;
      size_t base = ((size_t)bh * SEQ + q0w + rs) * HD;
      att[base + l31]      = (bf16)o0;
      att[base + 32 + l31] = (bf16)o1;
    }
  }
}

extern "C" void kernel_launch(void* const* d_in, const int* in_sizes, int n_in,
                              void* d_out, int out_size, void* d_ws, size_t ws_size,
                              hipStream_t stream) {
  const float* x  = (const float*)d_in[0];
  const int* pos  = (const int*)d_in[1];
  const float* Wq = (const float*)d_in[2];
  const float* Wk = (const float*)d_in[3];
  const float* Wv = (const float*)d_in[4];
  const float* Wo = (const float*)d_in[5];
  float* out = (float*)d_out;

  char* p = (char*)d_ws;
  bf16* xb   = (bf16*)p; p += (size_t)MTOT * DM * 2;
  bf16* wqb  = (bf16*)p; p += (size_t)DM * DM * 2;
  bf16* wkb  = (bf16*)p; p += (size_t)DM * DM * 2;
  bf16* wvb  = (bf16*)p; p += (size_t)DM * DM * 2;
  bf16* wob  = (bf16*)p; p += (size_t)DM * DM * 2;
  bf16* qb   = (bf16*)p; p += (size_t)MTOT * DM * 2;
  bf16* kb   = (bf16*)p; p += (size_t)MTOT * DM * 2;
  bf16* vtb  = (bf16*)p; p += (size_t)MTOT * DM * 2;
  bf16* attb = (bf16*)p; p += (size_t)MTOT * DM * 2;
  float2* tab = (float2*)p; p += (size_t)MTOT * 32 * sizeof(float2);
  (void)wkb; (void)wvb;

  prep_kernel<<<(2097152 + 131072 + 255) / 256, 256, 0, stream>>>(
      x, Wq, Wk, Wv, Wo, pos, xb, wqb, tab);

  gemm_qkv<<<dim3(12, MTOT / 256), 512, 0, stream>>>(xb, wqb, qb, kb, vtb, tab);

  attn_kernel<<<512, 512, 0, stream>>>(qb, kb, vtb, attb);

  gemm_out<<<dim3(DM / 64, MTOT / 128), 256, 0, stream>>>(attb, wob, out);
}

// Round 18
// 114.064 us; speedup vs baseline: 1.1018x; 1.0165x over previous
//
#include <hip/hip_runtime.h>
#include <hip/hip_bf16.h>

typedef __bf16 bf16;
typedef __bf16 bf16x4 __attribute__((ext_vector_type(4)));
typedef __bf16 bf16x8 __attribute__((ext_vector_type(8)));
typedef float f32x2 __attribute__((ext_vector_type(2)));
typedef float f32x4 __attribute__((ext_vector_type(4)));
typedef float f32x16 __attribute__((ext_vector_type(16)));
typedef unsigned int u32x4 __attribute__((ext_vector_type(4)));

#define NH 16
#define HD 64
#define SEQ 2048
#define DM 1024
#define MTOT 4096   // B*S

__device__ __forceinline__ void gload_lds16(const void* g, void* l) {
  __builtin_amdgcn_global_load_lds(
      (const __attribute__((address_space(1))) void*)g,
      (__attribute__((address_space(3))) void*)l, 16, 0, 0);
}

// ---------------- fused prep: x->bf16, 4 weights->bf16, RoPE table ----------------
__global__ __launch_bounds__(256) void prep_kernel(
    const float* __restrict__ x,
    const float* __restrict__ w0, const float* __restrict__ w1,
    const float* __restrict__ w2, const float* __restrict__ w3,
    const int* __restrict__ pos,
    bf16* __restrict__ xb, bf16* __restrict__ wb, float2* __restrict__ tab)
{
  int i = blockIdx.x * 256 + threadIdx.x;
  if (i < 1048576) {
    float4 v = reinterpret_cast<const float4*>(x)[i];
    bf16x4 o;
    o[0] = (bf16)v.x; o[1] = (bf16)v.y; o[2] = (bf16)v.z; o[3] = (bf16)v.w;
    *reinterpret_cast<bf16x4*>(xb + (size_t)i * 4) = o;
  } else if (i < 2097152) {
    int k = i - 1048576;
    int seg = k >> 18, j = k & 262143;
    const float* src = seg == 0 ? w0 : seg == 1 ? w1 : seg == 2 ? w2 : w3;
    float4 v = reinterpret_cast<const float4*>(src)[j];
    bf16x4 o;
    o[0] = (bf16)v.x; o[1] = (bf16)v.y; o[2] = (bf16)v.z; o[3] = (bf16)v.w;
    *reinterpret_cast<bf16x4*>(wb + ((size_t)seg << 20) + (size_t)j * 4) = o;
  } else if (i < 2097152 + 131072) {
    int k = i - 2097152;
    int m = k >> 5, i2 = k & 31;
    float pf = (float)pos[m];
    float inv = 1.0f / powf(10000.0f, (float)(2 * i2) * (1.0f / 64.0f));
    float a = pf * inv;
    tab[k] = make_float2(cosf(a), sinf(a));
  }
}

// ---------------- fused QKV projection GEMM, 256x256 tile, BK=64, 8-PHASE ----------------
// (frozen — verified r9/r11) grid (12, 16): proj = x>>2, n0 = (x&3)*256.
__global__ __launch_bounds__(512, 2) void gemm_qkv(
    const bf16* __restrict__ A, const bf16* __restrict__ wAll,
    bf16* __restrict__ outq, bf16* __restrict__ outk, bf16* __restrict__ outv,
    const float2* __restrict__ tab)
{
  __shared__ bf16 ABlds[2][2][2][8192];   // [A=0/B=1][parity][kk] 256x32 bf16 = 16 KB
  const int t = threadIdx.x;
  const int w = t >> 6;
  const int wm = w >> 2, wn = w & 3;
  const int lane = t & 63;
  const int lr = lane & 15;
  const int lg = lane >> 4;
  const int m0 = blockIdx.y * 256;
  const int proj = blockIdx.x >> 2;
  const int n0l = (blockIdx.x & 3) * 256;
  const char* Asrc = (const char*)A + (size_t)m0 * 2048;
  const char* Bsrc = (const char*)(wAll + ((size_t)proj << 20) + (size_t)n0l * DM);

  f32x4 acc[8][4] = {};
  bf16x8 bfr[4];

#define REG(AB_, PAR_, KK_) ((char*)ABlds + (((AB_)*4 + (PAR_)*2 + (KK_)) * 16384))

#define STAGE_HALF(AB_, T_, KK_)                                                   \
  {                                                                                \
    const char* gb_ = (AB_) ? Bsrc : Asrc;                                         \
    char* lb_ = REG(AB_, (T_) & 1, KK_);                                           \
    _Pragma("unroll")                                                              \
    for (int p_ = 0; p_ < 2; ++p_) {                                               \
      int o_ = (p_ * 512 + t) * 16;                                                \
      int r_ = o_ >> 6, c_ = o_ & 63;                                              \
      int cs_ = c_ ^ (((r_ >> 1) & 3) << 4);                                       \
      gload_lds16(gb_ + (size_t)r_ * 2048 + (T_) * 128 + (KK_) * 64 + cs_,         \
                  lb_ + o_);                                                       \
    }                                                                              \
  }

#define RDFRAG(DST, REGP, ROW)                                                     \
  {                                                                                \
    int row_ = (ROW);                                                              \
    int cb_ = (lg * 16) ^ (((row_ >> 1) & 3) << 4);                                \
    DST = *reinterpret_cast<const bf16x8*>((REGP) + row_ * 64 + cb_);              \
  }

#define PHASE(PAR, KK, MH, DOSTAGE, S_AB, S_T, S_KK, VM)                           \
  {                                                                                \
    bf16x8 af_[4];                                                                 \
    const char* areg_ = REG(0, PAR, KK);                                           \
    _Pragma("unroll")                                                              \
    for (int f_ = 0; f_ < 4; ++f_)                                                 \
      RDFRAG(af_[f_], areg_, wm * 128 + (MH) * 64 + f_ * 16 + lr);                 \
    if ((MH) == 0) {                                                               \
      const char* breg_ = REG(1, PAR, KK);                                         \
      _Pragma("unroll")                                                            \
      for (int j_ = 0; j_ < 4; ++j_)                                               \
        RDFRAG(bfr[j_], breg_, wn * 64 + j_ * 16 + lr);                            \
    }                                                                              \
    if (DOSTAGE) STAGE_HALF(S_AB, S_T, S_KK);                                      \
    if ((VM) == 8) asm volatile("s_waitcnt vmcnt(8)" ::: "memory");                \
    if ((VM) == 4) asm volatile("s_waitcnt vmcnt(4)" ::: "memory");                \
    if ((VM) == 0) asm volatile("s_waitcnt vmcnt(0)" ::: "memory");                \
    __builtin_amdgcn_sched_barrier(0);                                             \
    __builtin_amdgcn_s_barrier();                                                  \
    asm volatile("s_waitcnt lgkmcnt(0)" ::: "memory");                             \
    __builtin_amdgcn_sched_barrier(0);                                             \
    __builtin_amdgcn_s_setprio(1);                                                 \
    _Pragma("unroll")                                                              \
    for (int f_ = 0; f_ < 4; ++f_)                                                 \
      _Pragma("unroll")                                                            \
      for (int j_ = 0; j_ < 4; ++j_)                                               \
        acc[(MH) * 4 + f_][j_] = __builtin_amdgcn_mfma_f32_16x16x32_bf16(          \
            af_[f_], bfr[j_], acc[(MH) * 4 + f_][j_], 0, 0, 0);                    \
    __builtin_amdgcn_s_setprio(0);                                                 \
    __builtin_amdgcn_s_barrier();                                                  \
  }

  STAGE_HALF(0, 0, 0); STAGE_HALF(1, 0, 0);
  STAGE_HALF(0, 0, 1); STAGE_HALF(1, 0, 1);
  STAGE_HALF(0, 1, 0); STAGE_HALF(1, 1, 0);
  asm volatile("s_waitcnt vmcnt(4)" ::: "memory");
  __builtin_amdgcn_sched_barrier(0);
  __builtin_amdgcn_s_barrier();

  for (int i = 0; i < 7; ++i) {
    const int t1 = 2 * i + 1, t2 = 2 * i + 2, t3 = 2 * i + 3;
    PHASE(0, 0, 0, 1, 0, t1, 1, -1);
    PHASE(0, 0, 1, 1, 1, t1, 1,  8);
    PHASE(0, 1, 0, 1, 0, t2, 0, -1);
    PHASE(0, 1, 1, 1, 1, t2, 0,  8);
    PHASE(1, 0, 0, 1, 0, t2, 1, -1);
    PHASE(1, 0, 1, 1, 1, t2, 1,  8);
    PHASE(1, 1, 0, 1, 0, t3, 0, -1);
    PHASE(1, 1, 1, 1, 1, t3, 0,  8);
  }
  PHASE(0, 0, 0, 1, 0, 15, 1, -1);
  PHASE(0, 0, 1, 1, 1, 15, 1,  8);
  PHASE(0, 1, 0, 0, 0, 0, 0, -1);
  PHASE(0, 1, 1, 0, 0, 0, 0,  4);
  PHASE(1, 0, 0, 0, 0, 0, 0, -1);
  PHASE(1, 0, 1, 0, 0, 0, 0,  0);
  PHASE(1, 1, 0, 0, 0, 0, 0, -1);
  PHASE(1, 1, 1, 0, 0, 0, 0, -1);

#undef PHASE
#undef RDFRAG
#undef STAGE_HALF
#undef REG

  if (proj < 2) {
    bf16* outb = proj ? outk : outq;
#pragma unroll
    for (int j = 0; j < 4; ++j) {
      int nl = n0l + wn * 64 + j * 16 + lr;
      int h = nl >> 6, d = nl & 63;
      int i2 = d >> 1;
      bool odd = d & 1;
#pragma unroll
      for (int i = 0; i < 8; ++i) {
#pragma unroll
        for (int rr = 0; rr < 4; ++rr) {
          int m = m0 + wm * 128 + i * 16 + lg * 4 + rr;
          float v = acc[i][j][rr];
          float o = __shfl_xor(v, 1);
          float2 cs = tab[(m << 5) + i2];
          float res = odd ? (v * cs.x + o * cs.y) : (v * cs.x - o * cs.y);
          if (proj == 0) res *= 0.125f * 1.44269504f;   // 1/sqrt(hd) * log2(e)
          outb[((size_t)((m >> 11) * NH + h) * SEQ + (m & 2047)) * HD + d] = (bf16)res;
        }
      }
    }
  } else {
#pragma unroll
    for (int j = 0; j < 4; ++j) {
      int nl = n0l + wn * 64 + j * 16 + lr;
      int h = nl >> 6, d = nl & 63;
#pragma unroll
      for (int i = 0; i < 8; ++i) {
#pragma unroll
        for (int rr = 0; rr < 4; ++rr) {
          int m = m0 + wm * 128 + i * 16 + lg * 4 + rr;
          outv[((size_t)((m >> 11) * NH + h) * HD + d) * SEQ + (m & 2047)] = (bf16)acc[i][j][rr];
        }
      }
    }
  }
}

// ---------------- output projection GEMM: 64x64 tile, 1024 blocks (4/CU) ----------------
// single-barrier stage-early ring; 4 waves (2M x 2N), per-wave C = 32x32 (acc[2][2]).
__global__ __launch_bounds__(256) void gemm_out(
    const bf16* __restrict__ A, const bf16* __restrict__ Bw, float* __restrict__ outf)
{
  __shared__ bf16 As[2][64 * 32];
  __shared__ bf16 Bs[2][64 * 32];
  const int t = threadIdx.x;
  const int w = t >> 6;
  const int lane = t & 63;
  const int lr = lane & 15;
  const int lg = lane >> 4;
  const int m0 = blockIdx.y * 64;
  const int n0 = blockIdx.x * 64;
  const int wr = w >> 1, wc = w & 1;
  const char* Bb = (const char*)Bw;

  f32x4 acc[2][2] = {};

#define STAGE_OUT(KT, SLOT)                                                            \
  {                                                                                    \
    {                                                                                  \
      int o = t * 16;                                                                  \
      int r = o >> 6, cb = o & 63;                                                     \
      int m = m0 + r;                                                                  \
      const char* ga = (const char*)A +                                                \
          ((((size_t)(m >> 11) * NH + ((KT) >> 1)) * SEQ + (m & 2047)) * HD +          \
           ((KT) & 1) * 32) * 2 + cb;                                                  \
      gload_lds16(ga, (char*)As[SLOT] + o);                                            \
    }                                                                                  \
    {                                                                                  \
      int o = t * 16;                                                                  \
      int r = o >> 6, cb = o & 63;                                                     \
      gload_lds16(Bb + (size_t)(n0 + r) * 2048 + (KT) * 64 + cb, (char*)Bs[SLOT] + o); \
    }                                                                                  \
  }

  STAGE_OUT(0, 0);
  for (int kt = 0; kt < 32; ++kt) {
    // tile kt's loads (prologue or previous iteration) had a full compute phase to land
    asm volatile("s_waitcnt vmcnt(0)" ::: "memory");
    __builtin_amdgcn_sched_barrier(0);
    __builtin_amdgcn_s_barrier();
    if (kt + 1 < 32) STAGE_OUT(kt + 1, (kt + 1) & 1);

    const bf16* Abuf = As[kt & 1];
    const bf16* Bbuf = Bs[kt & 1];
    bf16x8 af[2], bfr[2];
#pragma unroll
    for (int f = 0; f < 2; ++f) {
      af[f]  = *reinterpret_cast<const bf16x8*>(Abuf + (wr * 32 + f * 16 + lr) * 32 + lg * 8);
      bfr[f] = *reinterpret_cast<const bf16x8*>(Bbuf + (wc * 32 + f * 16 + lr) * 32 + lg * 8);
    }
    __builtin_amdgcn_s_setprio(1);
#pragma unroll
    for (int i = 0; i < 2; ++i)
#pragma unroll
      for (int j = 0; j < 2; ++j)
        acc[i][j] = __builtin_amdgcn_mfma_f32_16x16x32_bf16(af[i], bfr[j], acc[i][j], 0, 0, 0);
    __builtin_amdgcn_s_setprio(0);
  }

#pragma unroll
  for (int j = 0; j < 2; ++j) {
    int n = n0 + wc * 32 + j * 16 + lr;
#pragma unroll
    for (int i = 0; i < 2; ++i) {
#pragma unroll
      for (int rr = 0; rr < 4; ++rr) {
        int m = m0 + wr * 32 + i * 16 + lg * 4 + rr;
        outf[(size_t)m * DM + n] = acc[i][j][rr];
      }
    }
  }
#undef STAGE_OUT
}

// ---------------- flash attention (frozen r15/r17: single-barrier pair ring) ----------------
__device__ __forceinline__ void stage512(const char* gRow0, size_t rowStrideB, int colByte0,
                                         char* lds, int t) {
  int o = t * 16;
  int r = o >> 7;
  int cb = o & 127;
  int cbs = cb ^ ((r & 7) << 4);
  gload_lds16(gRow0 + (size_t)r * rowStrideB + colByte0 + cbs, lds + o);
}

__device__ __forceinline__ bf16x8 frag64(const char* tile, int row, int colByte) {
  int b = row * 128 + (colByte ^ ((row & 7) << 4));
  return *reinterpret_cast<const bf16x8*>(tile + b);
}

__device__ __forceinline__ unsigned packw(float a, float b) {
  unsigned short la = __builtin_bit_cast(unsigned short, (bf16)a);
  unsigned short lb = __builtin_bit_cast(unsigned short, (bf16)b);
  return (unsigned)la | ((unsigned)lb << 16);
}

// v_permlane32_swap_b32: newA=(A_lo,B_lo), newB=(A_hi,B_hi).
// ONLY call with distinct-valued a,b (identical values risk register coalescing — r10 bug).
__device__ __forceinline__ void plswap(unsigned& a, unsigned& b) {
  asm volatile("v_permlane32_swap_b32 %0, %1" : "+v"(a), "+v"(b));
}

__device__ __forceinline__ void tile_step(const char* Kt, const char* Vt,
                                          const bf16x8* qf,
                                          f32x16& acc0, f32x16& acc1,
                                          float& mrow, float& lrow,
                                          int l31, int h, bool domask, int qloc) {
  f32x16 s0 = {}, s1 = {};
  __builtin_amdgcn_s_setprio(1);
#pragma unroll
  for (int s = 0; s < 4; ++s) {
    bf16x8 kf0 = frag64(Kt, l31, s * 32 + h * 16);
    bf16x8 kf1 = frag64(Kt, 32 + l31, s * 32 + h * 16);
    s0 = __builtin_amdgcn_mfma_f32_32x32x16_bf16(kf0, qf[s], s0, 0, 0, 0);
    s1 = __builtin_amdgcn_mfma_f32_32x32x16_bf16(kf1, qf[s], s1, 0, 0, 0);
  }
  __builtin_amdgcn_s_setprio(0);
  if (domask) {
#pragma unroll
    for (int reg = 0; reg < 16; ++reg) {
      int ro = (reg & 3) + 8 * (reg >> 2) + 4 * h;
      if (ro > qloc) s0[reg] = -1e30f;
      if (ro + 32 > qloc) s1[reg] = -1e30f;
    }
  }
  // ---- row max: nested triples (v_max3-friendly) ----
  float tm[16];
#pragma unroll
  for (int i = 0; i < 16; ++i) tm[i] = fmaxf(s0[i], s1[i]);
  float a0 = fmaxf(fmaxf(tm[0], tm[1]), tm[2]);
  float a1 = fmaxf(fmaxf(tm[3], tm[4]), tm[5]);
  float a2 = fmaxf(fmaxf(tm[6], tm[7]), tm[8]);
  float a3 = fmaxf(fmaxf(tm[9], tm[10]), tm[11]);
  float a4 = fmaxf(fmaxf(tm[12], tm[13]), tm[14]);
  float b0 = fmaxf(fmaxf(a0, a1), a2);
  float b1 = fmaxf(fmaxf(a3, a4), tm[15]);
  float tmax = fmaxf(b0, b1);
  float rmax = fmaxf(tmax, __shfl_xor(tmax, 32));

  bool need = __any(rmax > mrow + 11.5f);   // defer-max (T13), log2 domain
  if (need) {
    float mnew = fmaxf(mrow, rmax);
    float osc = exp2f(mrow - mnew);
#pragma unroll
    for (int reg = 0; reg < 16; ++reg) {
      int rs = (reg & 3) + 8 * (reg >> 2) + 4 * h;
      float o = __shfl(osc, rs);
      acc0[reg] *= o;
      acc1[reg] *= o;
    }
    lrow *= osc;
    mrow = mnew;
  }
#pragma unroll
  for (int i = 0; i < 16; ++i) {
    s0[i] = exp2f(s0[i] - mrow);
    s1[i] = exp2f(s1[i] - mrow);
  }
  // ---- row sum: packed-f32 tree ----
  {
    const f32x2* p0 = reinterpret_cast<const f32x2*>(&s0);
    const f32x2* p1 = reinterpret_cast<const f32x2*>(&s1);
    f32x2 tp[8];
#pragma unroll
    for (int i = 0; i < 8; ++i) tp[i] = p0[i] + p1[i];
    tp[0] += tp[4]; tp[1] += tp[5]; tp[2] += tp[6]; tp[3] += tp[7];
    tp[0] += tp[2]; tp[1] += tp[3];
    tp[0] += tp[1];
    float rs = tp[0][0] + tp[0][1];
    lrow += rs + __shfl_xor(rs, 32);
  }

  // ---- P -> A-fragment repack via permlane32_swap (proven r11) ----
  unsigned W0[4][2], W1[4][2];
#pragma unroll
  for (int sp = 0; sp < 4; ++sp)
#pragma unroll
    for (int u = 0; u < 2; ++u) {
      W0[sp][u] = packw(s0[sp * 4 + 2 * u], s0[sp * 4 + 2 * u + 1]);
      W1[sp][u] = packw(s1[sp * 4 + 2 * u], s1[sp * 4 + 2 * u + 1]);
    }
  __builtin_amdgcn_s_setprio(1);
#pragma unroll
  for (int ks = 0; ks < 4; ++ks) {
    const unsigned (*W)[2] = (ks < 2) ? W0 : W1;
    const int c = ks & 1;
    unsigned a0w = W[2 * c][0], b0w = W[2 * c + 1][0];
    unsigned a1w = W[2 * c][1], b1w = W[2 * c + 1][1];
    plswap(a0w, b0w);
    plswap(a1w, b1w);
    u32x4 pw = {a0w, a1w, b0w, b1w};
    bf16x8 pf = __builtin_bit_cast(bf16x8, pw);
    bf16x8 vf0 = frag64(Vt, l31, ks * 32 + h * 16);
    bf16x8 vf1 = frag64(Vt, 32 + l31, ks * 32 + h * 16);
    acc0 = __builtin_amdgcn_mfma_f32_32x32x16_bf16(pf, vf0, acc0, 0, 0, 0);
    acc1 = __builtin_amdgcn_mfma_f32_32x32x16_bf16(pf, vf1, acc1, 0, 0, 0);
  }
  __builtin_amdgcn_s_setprio(0);
}

__global__ __launch_bounds__(512, 4) void attn_kernel(
    const bf16* __restrict__ q, const bf16* __restrict__ k,
    const bf16* __restrict__ vt, bf16* __restrict__ att)
{
  __shared__ __align__(16) char pool[65536];
  const int t = threadIdx.x;
  const int w = t >> 6;
  const int wsub = w & 3;
  const int par = w >> 2;
  const int lane = t & 63;
  const int l31 = lane & 31;
  const int h = lane >> 5;

  // XCD-local bh mapping (r14): all 16 blocks of a bh on one XCD; complementary pairing kept.
  const int id = blockIdx.x;
  const int bh = (id & 7) + 8 * ((id >> 3) & 3);
  const int rem = id >> 5;           // 0..15
  const int halfb = rem >> 3;        // 0/1
  const int jj = rem & 7;
  const int j = halfb ? jj : 15 - jj;

  const int strip = 2 * j + (wsub >> 1);
  const int myN = strip + 1;
  const int npair = j + 1;
  const int q0w = j * 128 + wsub * 32;
  const int qloc = (wsub & 1) * 32 + l31;

  const bf16* qb = q + (size_t)bh * SEQ * HD;
  const char* kbB = (const char*)(k + (size_t)bh * SEQ * HD);
  const char* vbB = (const char*)(vt + (size_t)bh * HD * SEQ);

  bf16x8 qf[4];
#pragma unroll
  for (int s = 0; s < 4; ++s)
    qf[s] = *reinterpret_cast<const bf16x8*>(qb + (size_t)(q0w + l31) * HD + s * 16 + h * 8);

  f32x16 acc0 = {}, acc1 = {};
  float mrow = -1e30f, lrow = 0.f;

  // prologue: stage pair 0 (tiles 0,1)
  stage512(kbB, 128, 0, pool + 0 * 8192, t);
  stage512(vbB, 4096, 0, pool + 32768 + 0 * 8192, t);
  stage512(kbB + 8192, 128, 0, pool + 1 * 8192, t);
  stage512(vbB, 4096, 128, pool + 32768 + 1 * 8192, t);

  for (int u = 0; u < npair; ++u) {
    asm volatile("s_waitcnt vmcnt(0)" ::: "memory");
    __builtin_amdgcn_sched_barrier(0);
    __builtin_amdgcn_s_barrier();
    if (u + 1 < npair) {
      int nt = 2 * u + 2;
      stage512(kbB + (size_t)nt * 8192, 128, 0, pool + (nt & 3) * 8192, t);
      stage512(vbB, 4096, nt * 128, pool + 32768 + (nt & 3) * 8192, t);
      stage512(kbB + (size_t)(nt + 1) * 8192, 128, 0, pool + ((nt + 1) & 3) * 8192, t);
      stage512(vbB, 4096, (nt + 1) * 128, pool + 32768 + ((nt + 1) & 3) * 8192, t);
    }
    const int tt = 2 * u + par;
    if (tt < myN)
      tile_step(pool + (tt & 3) * 8192, pool + 32768 + (tt & 3) * 8192, qf,
                acc0, acc1, mrow, lrow, l31, h, tt == strip, qloc);
  }

  // all waves must finish reading K/V from pool before the merge overwrites it
  __syncthreads();

  float* mb = (float*)pool;
  float* reg = mb + wsub * (34 * 64);
  if (par == 1) {
#pragma unroll
    for (int i = 0; i < 16; ++i) reg[i * 64 + lane] = acc0[i];
#pragma unroll
    for (int i = 0; i < 16; ++i) reg[(16 + i) * 64 + lane] = acc1[i];
    reg[32 * 64 + lane] = mrow;
    reg[33 * 64 + lane] = lrow;
  }
  __syncthreads();
  if (par == 0) {
    float mB = reg[32 * 64 + lane];
    float lB = reg[33 * 64 + lane];
    float mM = fmaxf(mrow, mB);
    float alpha = exp2f(mrow - mM);
    float beta  = exp2f(mB - mM);
    float linv = 1.0f / (alpha * lrow + beta * lB);
#pragma unroll
    for (int rg = 0; rg < 16; ++rg) {
      int rs = (rg & 3) + 8 * (rg >> 2) + 4 * h;
      float a  = __shfl(alpha, rs);
      float b  = __shfl(beta, rs);
      float li = __shfl(linv, rs);
      float o0 = (a * acc0[rg] + b * reg[rg * 64 + lane]) * li;
      float o1 = (a * acc1[rg] + b * reg[(16 + rg) * 64 + lane]) * li;
      size_t base = ((size_t)bh * SEQ + q0w + rs) * HD;
      att[base + l31]      = (bf16)o0;
      att[base + 32 + l31] = (bf16)o1;
    }
  }
}

extern "C" void kernel_launch(void* const* d_in, const int* in_sizes, int n_in,
                              void* d_out, int out_size, void* d_ws, size_t ws_size,
                              hipStream_t stream) {
  const float* x  = (const float*)d_in[0];
  const int* pos  = (const int*)d_in[1];
  const float* Wq = (const float*)d_in[2];
  const float* Wk = (const float*)d_in[3];
  const float* Wv = (const float*)d_in[4];
  const float* Wo = (const float*)d_in[5];
  float* out = (float*)d_out;

  char* p = (char*)d_ws;
  bf16* xb   = (bf16*)p; p += (size_t)MTOT * DM * 2;
  bf16* wqb  = (bf16*)p; p += (size_t)DM * DM * 2;
  bf16* wkb  = (bf16*)p; p += (size_t)DM * DM * 2;
  bf16* wvb  = (bf16*)p; p += (size_t)DM * DM * 2;
  bf16* wob  = (bf16*)p; p += (size_t)DM * DM * 2;
  bf16* qb   = (bf16*)p; p += (size_t)MTOT * DM * 2;
  bf16* kb   = (bf16*)p; p += (size_t)MTOT * DM * 2;
  bf16* vtb  = (bf16*)p; p += (size_t)MTOT * DM * 2;
  bf16* attb = (bf16*)p; p += (size_t)MTOT * DM * 2;
  float2* tab = (float2*)p; p += (size_t)MTOT * 32 * sizeof(float2);
  (void)wkb; (void)wvb;

  prep_kernel<<<(2097152 + 131072 + 255) / 256, 256, 0, stream>>>(
      x, Wq, Wk, Wv, Wo, pos, xb, wqb, tab);

  gemm_qkv<<<dim3(12, MTOT / 256), 512, 0, stream>>>(xb, wqb, qb, kb, vtb, tab);

  attn_kernel<<<512, 512, 0, stream>>>(qb, kb, vtb, attb);

  gemm_out<<<dim3(DM / 64, MTOT / 64), 256, 0, stream>>>(attb, wob, out);
}

// Round 19
// 111.799 us; speedup vs baseline: 1.1241x; 1.0203x over previous
//
#include <hip/hip_runtime.h>
#include <hip/hip_bf16.h>

typedef __bf16 bf16;
typedef __bf16 bf16x4 __attribute__((ext_vector_type(4)));
typedef __bf16 bf16x8 __attribute__((ext_vector_type(8)));
typedef float f32x2 __attribute__((ext_vector_type(2)));
typedef float f32x4 __attribute__((ext_vector_type(4)));
typedef float f32x16 __attribute__((ext_vector_type(16)));
typedef unsigned int u32x4 __attribute__((ext_vector_type(4)));

#define NH 16
#define HD 64
#define SEQ 2048
#define DM 1024
#define MTOT 4096   // B*S

__device__ __forceinline__ void gload_lds16(const void* g, void* l) {
  __builtin_amdgcn_global_load_lds(
      (const __attribute__((address_space(1))) void*)g,
      (__attribute__((address_space(3))) void*)l, 16, 0, 0);
}

// ---------------- fused prep: x->bf16, 4 weights->bf16, RoPE table ----------------
__global__ __launch_bounds__(256) void prep_kernel(
    const float* __restrict__ x,
    const float* __restrict__ w0, const float* __restrict__ w1,
    const float* __restrict__ w2, const float* __restrict__ w3,
    const int* __restrict__ pos,
    bf16* __restrict__ xb, bf16* __restrict__ wb, float2* __restrict__ tab)
{
  int i = blockIdx.x * 256 + threadIdx.x;
  if (i < 1048576) {
    float4 v = reinterpret_cast<const float4*>(x)[i];
    bf16x4 o;
    o[0] = (bf16)v.x; o[1] = (bf16)v.y; o[2] = (bf16)v.z; o[3] = (bf16)v.w;
    *reinterpret_cast<bf16x4*>(xb + (size_t)i * 4) = o;
  } else if (i < 2097152) {
    int k = i - 1048576;
    int seg = k >> 18, j = k & 262143;
    const float* src = seg == 0 ? w0 : seg == 1 ? w1 : seg == 2 ? w2 : w3;
    float4 v = reinterpret_cast<const float4*>(src)[j];
    bf16x4 o;
    o[0] = (bf16)v.x; o[1] = (bf16)v.y; o[2] = (bf16)v.z; o[3] = (bf16)v.w;
    *reinterpret_cast<bf16x4*>(wb + ((size_t)seg << 20) + (size_t)j * 4) = o;
  } else if (i < 2097152 + 131072) {
    int k = i - 2097152;
    int m = k >> 5, i2 = k & 31;
    float pf = (float)pos[m];
    float inv = 1.0f / powf(10000.0f, (float)(2 * i2) * (1.0f / 64.0f));
    float a = pf * inv;
    tab[k] = make_float2(cosf(a), sinf(a));
  }
}

// ---------------- fused QKV projection GEMM, 128x128 tile, BK=64, 4-PHASE ----------------
// grid (24, 32): proj = x>>3, n0 = (x&7)*128; m0 = y*128. 512 thr = 8 waves (2M x 4N),
// per-wave C = 64x32 (acc[4][2]). LDS regions [A|B][parity][kk] 128x32 bf16 = 8 KB each,
// total 64 KB -> 2 blocks/CU, 768 blocks = full 256-CU coverage.
// 4 phases per 2 K-tiles; stages: P00->(2i+1,k1), P01->(2i+2,k0), P10->(2i+2,k1),
// P11->(2i+3,k0) — each targets the region read one phase earlier (behind its barrier).
// Certify-next-phase vmcnt(4) steady state (6 outstanding - 2 oldest); prologue 6 loads
// + vmcnt(4); epilogue drains 4 -> 2 -> 0 -> none.
__global__ __launch_bounds__(512, 2) void gemm_qkv(
    const bf16* __restrict__ A, const bf16* __restrict__ wAll,
    bf16* __restrict__ outq, bf16* __restrict__ outk, bf16* __restrict__ outv,
    const float2* __restrict__ tab)
{
  __shared__ bf16 ABlds[2][2][2][4096];   // [A=0/B=1][parity][kk] 128x32 bf16 = 8 KB
  const int t = threadIdx.x;
  const int w = t >> 6;
  const int wm = w >> 2, wn = w & 3;
  const int lane = t & 63;
  const int lr = lane & 15;
  const int lg = lane >> 4;
  const int m0 = blockIdx.y * 128;
  const int proj = blockIdx.x >> 3;
  const int n0l = (blockIdx.x & 7) * 128;
  const char* Asrc = (const char*)A + (size_t)m0 * 2048;
  const char* Bsrc = (const char*)(wAll + ((size_t)proj << 20) + (size_t)n0l * DM);

  f32x4 acc[4][2] = {};

#define REG(AB_, PAR_, KK_) ((char*)ABlds + (((AB_)*4 + (PAR_)*2 + (KK_)) * 8192))

#define STAGE2(AB_, T_, KK_)                                                       \
  {                                                                                \
    const char* gb_ = (AB_) ? Bsrc : Asrc;                                         \
    char* lb_ = REG(AB_, (T_) & 1, KK_);                                           \
    int o_ = t * 16;                                                               \
    int r_ = o_ >> 6, c_ = o_ & 63;                                                \
    int cs_ = c_ ^ (((r_ >> 1) & 3) << 4);                                         \
    gload_lds16(gb_ + (size_t)r_ * 2048 + (T_) * 128 + (KK_) * 64 + cs_,           \
                lb_ + o_);                                                         \
  }

#define RDFRAG(DST, REGP, ROW)                                                     \
  {                                                                                \
    int row_ = (ROW);                                                              \
    int cb_ = (lg * 16) ^ (((row_ >> 1) & 3) << 4);                                \
    DST = *reinterpret_cast<const bf16x8*>((REGP) + row_ * 64 + cb_);              \
  }

// PHASE2(PAR, KK, DOSTAGE, S_T, S_KK, VM): read (tile parity PAR, kk KK), optionally
// stage A+B of (S_T,S_KK), vmcnt(VM), barrier, lgkm drain, 8 MFMA, barrier.
#define PHASE2(PAR, KK, DOSTAGE, S_T, S_KK, VM)                                    \
  {                                                                                \
    bf16x8 af_[4], bf_[2];                                                         \
    const char* areg_ = REG(0, PAR, KK);                                           \
    _Pragma("unroll")                                                              \
    for (int f_ = 0; f_ < 4; ++f_)                                                 \
      RDFRAG(af_[f_], areg_, wm * 64 + f_ * 16 + lr);                              \
    const char* breg_ = REG(1, PAR, KK);                                           \
    _Pragma("unroll")                                                              \
    for (int j_ = 0; j_ < 2; ++j_)                                                 \
      RDFRAG(bf_[j_], breg_, wn * 32 + j_ * 16 + lr);                              \
    if (DOSTAGE) { STAGE2(0, S_T, S_KK); STAGE2(1, S_T, S_KK); }                   \
    if ((VM) == 4) asm volatile("s_waitcnt vmcnt(4)" ::: "memory");                \
    if ((VM) == 2) asm volatile("s_waitcnt vmcnt(2)" ::: "memory");                \
    if ((VM) == 0) asm volatile("s_waitcnt vmcnt(0)" ::: "memory");                \
    __builtin_amdgcn_sched_barrier(0);                                             \
    __builtin_amdgcn_s_barrier();                                                  \
    asm volatile("s_waitcnt lgkmcnt(0)" ::: "memory");                             \
    __builtin_amdgcn_sched_barrier(0);                                             \
    __builtin_amdgcn_s_setprio(1);                                                 \
    _Pragma("unroll")                                                              \
    for (int f_ = 0; f_ < 4; ++f_)                                                 \
      _Pragma("unroll")                                                            \
      for (int j_ = 0; j_ < 2; ++j_)                                               \
        acc[f_][j_] = __builtin_amdgcn_mfma_f32_16x16x32_bf16(                     \
            af_[f_], bf_[j_], acc[f_][j_], 0, 0, 0);                               \
    __builtin_amdgcn_s_setprio(0);                                                 \
    __builtin_amdgcn_s_barrier();                                                  \
  }

  // prologue: (0,k0), (0,k1), (1,k0) A+B = 6 loads; certify (0,k0)
  STAGE2(0, 0, 0); STAGE2(1, 0, 0);
  STAGE2(0, 0, 1); STAGE2(1, 0, 1);
  STAGE2(0, 1, 0); STAGE2(1, 1, 0);
  asm volatile("s_waitcnt vmcnt(4)" ::: "memory");
  __builtin_amdgcn_sched_barrier(0);
  __builtin_amdgcn_s_barrier();

  for (int i = 0; i < 7; ++i) {
    const int t1 = 2 * i + 1, t2 = 2 * i + 2, t3 = 2 * i + 3;
    PHASE2(0, 0, 1, t1, 1, 4);   // read (2i,k0)  ; stage (2i+1,k1)
    PHASE2(0, 1, 1, t2, 0, 4);   // read (2i,k1)  ; stage (2i+2,k0)
    PHASE2(1, 0, 1, t2, 1, 4);   // read (2i+1,k0); stage (2i+2,k1)
    PHASE2(1, 1, 1, t3, 0, 4);   // read (2i+1,k1); stage (2i+3,k0)
  }
  // epilogue: tiles 14,15 — stage only (15,k1); drain 4 -> 2 -> 0 -> none
  PHASE2(0, 0, 1, 15, 1, 4);
  PHASE2(0, 1, 0, 0, 0, 2);
  PHASE2(1, 0, 0, 0, 0, 0);
  PHASE2(1, 1, 0, 0, 0, -1);

#undef PHASE2
#undef RDFRAG
#undef STAGE2
#undef REG

  if (proj < 2) {
    bf16* outb = proj ? outk : outq;
#pragma unroll
    for (int j = 0; j < 2; ++j) {
      int nl = n0l + wn * 32 + j * 16 + lr;
      int h = nl >> 6, d = nl & 63;
      int i2 = d >> 1;
      bool odd = d & 1;
#pragma unroll
      for (int i = 0; i < 4; ++i) {
#pragma unroll
        for (int rr = 0; rr < 4; ++rr) {
          int m = m0 + wm * 64 + i * 16 + lg * 4 + rr;
          float v = acc[i][j][rr];
          float o = __shfl_xor(v, 1);
          float2 cs = tab[(m << 5) + i2];
          float res = odd ? (v * cs.x + o * cs.y) : (v * cs.x - o * cs.y);
          if (proj == 0) res *= 0.125f * 1.44269504f;   // 1/sqrt(hd) * log2(e)
          outb[((size_t)((m >> 11) * NH + h) * SEQ + (m & 2047)) * HD + d] = (bf16)res;
        }
      }
    }
  } else {
#pragma unroll
    for (int j = 0; j < 2; ++j) {
      int nl = n0l + wn * 32 + j * 16 + lr;
      int h = nl >> 6, d = nl & 63;
#pragma unroll
      for (int i = 0; i < 4; ++i) {
#pragma unroll
        for (int rr = 0; rr < 4; ++rr) {
          int m = m0 + wm * 64 + i * 16 + lg * 4 + rr;
          outv[((size_t)((m >> 11) * NH + h) * HD + d) * SEQ + (m & 2047)] = (bf16)acc[i][j][rr];
        }
      }
    }
  }
}

// ---------------- output projection GEMM: 64x64 tile, 1024 blocks (frozen r18) ----------------
__global__ __launch_bounds__(256) void gemm_out(
    const bf16* __restrict__ A, const bf16* __restrict__ Bw, float* __restrict__ outf)
{
  __shared__ bf16 As[2][64 * 32];
  __shared__ bf16 Bs[2][64 * 32];
  const int t = threadIdx.x;
  const int w = t >> 6;
  const int lane = t & 63;
  const int lr = lane & 15;
  const int lg = lane >> 4;
  const int m0 = blockIdx.y * 64;
  const int n0 = blockIdx.x * 64;
  const int wr = w >> 1, wc = w & 1;
  const char* Bb = (const char*)Bw;

  f32x4 acc[2][2] = {};

#define STAGE_OUT(KT, SLOT)                                                            \
  {                                                                                    \
    {                                                                                  \
      int o = t * 16;                                                                  \
      int r = o >> 6, cb = o & 63;                                                     \
      int m = m0 + r;                                                                  \
      const char* ga = (const char*)A +                                                \
          ((((size_t)(m >> 11) * NH + ((KT) >> 1)) * SEQ + (m & 2047)) * HD +          \
           ((KT) & 1) * 32) * 2 + cb;                                                  \
      gload_lds16(ga, (char*)As[SLOT] + o);                                            \
    }                                                                                  \
    {                                                                                  \
      int o = t * 16;                                                                  \
      int r = o >> 6, cb = o & 63;                                                     \
      gload_lds16(Bb + (size_t)(n0 + r) * 2048 + (KT) * 64 + cb, (char*)Bs[SLOT] + o); \
    }                                                                                  \
  }

  STAGE_OUT(0, 0);
  for (int kt = 0; kt < 32; ++kt) {
    asm volatile("s_waitcnt vmcnt(0)" ::: "memory");
    __builtin_amdgcn_sched_barrier(0);
    __builtin_amdgcn_s_barrier();
    if (kt + 1 < 32) STAGE_OUT(kt + 1, (kt + 1) & 1);

    const bf16* Abuf = As[kt & 1];
    const bf16* Bbuf = Bs[kt & 1];
    bf16x8 af[2], bfr[2];
#pragma unroll
    for (int f = 0; f < 2; ++f) {
      af[f]  = *reinterpret_cast<const bf16x8*>(Abuf + (wr * 32 + f * 16 + lr) * 32 + lg * 8);
      bfr[f] = *reinterpret_cast<const bf16x8*>(Bbuf + (wc * 32 + f * 16 + lr) * 32 + lg * 8);
    }
    __builtin_amdgcn_s_setprio(1);
#pragma unroll
    for (int i = 0; i < 2; ++i)
#pragma unroll
      for (int j = 0; j < 2; ++j)
        acc[i][j] = __builtin_amdgcn_mfma_f32_16x16x32_bf16(af[i], bfr[j], acc[i][j], 0, 0, 0);
    __builtin_amdgcn_s_setprio(0);
  }

#pragma unroll
  for (int j = 0; j < 2; ++j) {
    int n = n0 + wc * 32 + j * 16 + lr;
#pragma unroll
    for (int i = 0; i < 2; ++i) {
#pragma unroll
      for (int rr = 0; rr < 4; ++rr) {
        int m = m0 + wr * 32 + i * 16 + lg * 4 + rr;
        outf[(size_t)m * DM + n] = acc[i][j][rr];
      }
    }
  }
#undef STAGE_OUT
}

// ---------------- flash attention (frozen r15/r17: single-barrier pair ring) ----------------
__device__ __forceinline__ void stage512(const char* gRow0, size_t rowStrideB, int colByte0,
                                         char* lds, int t) {
  int o = t * 16;
  int r = o >> 7;
  int cb = o & 127;
  int cbs = cb ^ ((r & 7) << 4);
  gload_lds16(gRow0 + (size_t)r * rowStrideB + colByte0 + cbs, lds + o);
}

__device__ __forceinline__ bf16x8 frag64(const char* tile, int row, int colByte) {
  int b = row * 128 + (colByte ^ ((row & 7) << 4));
  return *reinterpret_cast<const bf16x8*>(tile + b);
}

__device__ __forceinline__ unsigned packw(float a, float b) {
  unsigned short la = __builtin_bit_cast(unsigned short, (bf16)a);
  unsigned short lb = __builtin_bit_cast(unsigned short, (bf16)b);
  return (unsigned)la | ((unsigned)lb << 16);
}

// v_permlane32_swap_b32: newA=(A_lo,B_lo), newB=(A_hi,B_hi).
// ONLY call with distinct-valued a,b (identical values risk register coalescing — r10 bug).
__device__ __forceinline__ void plswap(unsigned& a, unsigned& b) {
  asm volatile("v_permlane32_swap_b32 %0, %1" : "+v"(a), "+v"(b));
}

__device__ __forceinline__ void tile_step(const char* Kt, const char* Vt,
                                          const bf16x8* qf,
                                          f32x16& acc0, f32x16& acc1,
                                          float& mrow, float& lrow,
                                          int l31, int h, bool domask, int qloc) {
  f32x16 s0 = {}, s1 = {};
  __builtin_amdgcn_s_setprio(1);
#pragma unroll
  for (int s = 0; s < 4; ++s) {
    bf16x8 kf0 = frag64(Kt, l31, s * 32 + h * 16);
    bf16x8 kf1 = frag64(Kt, 32 + l31, s * 32 + h * 16);
    s0 = __builtin_amdgcn_mfma_f32_32x32x16_bf16(kf0, qf[s], s0, 0, 0, 0);
    s1 = __builtin_amdgcn_mfma_f32_32x32x16_bf16(kf1, qf[s], s1, 0, 0, 0);
  }
  __builtin_amdgcn_s_setprio(0);
  if (domask) {
#pragma unroll
    for (int reg = 0; reg < 16; ++reg) {
      int ro = (reg & 3) + 8 * (reg >> 2) + 4 * h;
      if (ro > qloc) s0[reg] = -1e30f;
      if (ro + 32 > qloc) s1[reg] = -1e30f;
    }
  }
  float tm[16];
#pragma unroll
  for (int i = 0; i < 16; ++i) tm[i] = fmaxf(s0[i], s1[i]);
  float a0 = fmaxf(fmaxf(tm[0], tm[1]), tm[2]);
  float a1 = fmaxf(fmaxf(tm[3], tm[4]), tm[5]);
  float a2 = fmaxf(fmaxf(tm[6], tm[7]), tm[8]);
  float a3 = fmaxf(fmaxf(tm[9], tm[10]), tm[11]);
  float a4 = fmaxf(fmaxf(tm[12], tm[13]), tm[14]);
  float b0 = fmaxf(fmaxf(a0, a1), a2);
  float b1 = fmaxf(fmaxf(a3, a4), tm[15]);
  float tmax = fmaxf(b0, b1);
  float rmax = fmaxf(tmax, __shfl_xor(tmax, 32));

  bool need = __any(rmax > mrow + 11.5f);   // defer-max (T13), log2 domain
  if (need) {
    float mnew = fmaxf(mrow, rmax);
    float osc = exp2f(mrow - mnew);
#pragma unroll
    for (int reg = 0; reg < 16; ++reg) {
      int rs = (reg & 3) + 8 * (reg >> 2) + 4 * h;
      float o = __shfl(osc, rs);
      acc0[reg] *= o;
      acc1[reg] *= o;
    }
    lrow *= osc;
    mrow = mnew;
  }
#pragma unroll
  for (int i = 0; i < 16; ++i) {
    s0[i] = exp2f(s0[i] - mrow);
    s1[i] = exp2f(s1[i] - mrow);
  }
  {
    const f32x2* p0 = reinterpret_cast<const f32x2*>(&s0);
    const f32x2* p1 = reinterpret_cast<const f32x2*>(&s1);
    f32x2 tp[8];
#pragma unroll
    for (int i = 0; i < 8; ++i) tp[i] = p0[i] + p1[i];
    tp[0] += tp[4]; tp[1] += tp[5]; tp[2] += tp[6]; tp[3] += tp[7];
    tp[0] += tp[2]; tp[1] += tp[3];
    tp[0] += tp[1];
    float rs = tp[0][0] + tp[0][1];
    lrow += rs + __shfl_xor(rs, 32);
  }

  unsigned W0[4][2], W1[4][2];
#pragma unroll
  for (int sp = 0; sp < 4; ++sp)
#pragma unroll
    for (int u = 0; u < 2; ++u) {
      W0[sp][u] = packw(s0[sp * 4 + 2 * u], s0[sp * 4 + 2 * u + 1]);
      W1[sp][u] = packw(s1[sp * 4 + 2 * u], s1[sp * 4 + 2 * u + 1]);
    }
  __builtin_amdgcn_s_setprio(1);
#pragma unroll
  for (int ks = 0; ks < 4; ++ks) {
    const unsigned (*W)[2] = (ks < 2) ? W0 : W1;
    const int c = ks & 1;
    unsigned a0w = W[2 * c][0], b0w = W[2 * c + 1][0];
    unsigned a1w = W[2 * c][1], b1w = W[2 * c + 1][1];
    plswap(a0w, b0w);
    plswap(a1w, b1w);
    u32x4 pw = {a0w, a1w, b0w, b1w};
    bf16x8 pf = __builtin_bit_cast(bf16x8, pw);
    bf16x8 vf0 = frag64(Vt, l31, ks * 32 + h * 16);
    bf16x8 vf1 = frag64(Vt, 32 + l31, ks * 32 + h * 16);
    acc0 = __builtin_amdgcn_mfma_f32_32x32x16_bf16(pf, vf0, acc0, 0, 0, 0);
    acc1 = __builtin_amdgcn_mfma_f32_32x32x16_bf16(pf, vf1, acc1, 0, 0, 0);
  }
  __builtin_amdgcn_s_setprio(0);
}

__global__ __launch_bounds__(512, 4) void attn_kernel(
    const bf16* __restrict__ q, const bf16* __restrict__ k,
    const bf16* __restrict__ vt, bf16* __restrict__ att)
{
  __shared__ __align__(16) char pool[65536];
  const int t = threadIdx.x;
  const int w = t >> 6;
  const int wsub = w & 3;
  const int par = w >> 2;
  const int lane = t & 63;
  const int l31 = lane & 31;
  const int h = lane >> 5;

  // XCD-local bh mapping (r14): all 16 blocks of a bh on one XCD; complementary pairing kept.
  const int id = blockIdx.x;
  const int bh = (id & 7) + 8 * ((id >> 3) & 3);
  const int rem = id >> 5;           // 0..15
  const int halfb = rem >> 3;        // 0/1
  const int jj = rem & 7;
  const int j = halfb ? jj : 15 - jj;

  const int strip = 2 * j + (wsub >> 1);
  const int myN = strip + 1;
  const int npair = j + 1;
  const int q0w = j * 128 + wsub * 32;
  const int qloc = (wsub & 1) * 32 + l31;

  const bf16* qb = q + (size_t)bh * SEQ * HD;
  const char* kbB = (const char*)(k + (size_t)bh * SEQ * HD);
  const char* vbB = (const char*)(vt + (size_t)bh * HD * SEQ);

  bf16x8 qf[4];
#pragma unroll
  for (int s = 0; s < 4; ++s)
    qf[s] = *reinterpret_cast<const bf16x8*>(qb + (size_t)(q0w + l31) * HD + s * 16 + h * 8);

  f32x16 acc0 = {}, acc1 = {};
  float mrow = -1e30f, lrow = 0.f;

  // prologue: stage pair 0 (tiles 0,1)
  stage512(kbB, 128, 0, pool + 0 * 8192, t);
  stage512(vbB, 4096, 0, pool + 32768 + 0 * 8192, t);
  stage512(kbB + 8192, 128, 0, pool + 1 * 8192, t);
  stage512(vbB, 4096, 128, pool + 32768 + 1 * 8192, t);

  for (int u = 0; u < npair; ++u) {
    asm volatile("s_waitcnt vmcnt(0)" ::: "memory");
    __builtin_amdgcn_sched_barrier(0);
    __builtin_amdgcn_s_barrier();
    if (u + 1 < npair) {
      int nt = 2 * u + 2;
      stage512(kbB + (size_t)nt * 8192, 128, 0, pool + (nt & 3) * 8192, t);
      stage512(vbB, 4096, nt * 128, pool + 32768 + (nt & 3) * 8192, t);
      stage512(kbB + (size_t)(nt + 1) * 8192, 128, 0, pool + ((nt + 1) & 3) * 8192, t);
      stage512(vbB, 4096, (nt + 1) * 128, pool + 32768 + ((nt + 1) & 3) * 8192, t);
    }
    const int tt = 2 * u + par;
    if (tt < myN)
      tile_step(pool + (tt & 3) * 8192, pool + 32768 + (tt & 3) * 8192, qf,
                acc0, acc1, mrow, lrow, l31, h, tt == strip, qloc);
  }

  // all waves must finish reading K/V from pool before the merge overwrites it
  __syncthreads();

  float* mb = (float*)pool;
  float* reg = mb + wsub * (34 * 64);
  if (par == 1) {
#pragma unroll
    for (int i = 0; i < 16; ++i) reg[i * 64 + lane] = acc0[i];
#pragma unroll
    for (int i = 0; i < 16; ++i) reg[(16 + i) * 64 + lane] = acc1[i];
    reg[32 * 64 + lane] = mrow;
    reg[33 * 64 + lane] = lrow;
  }
  __syncthreads();
  if (par == 0) {
    float mB = reg[32 * 64 + lane];
    float lB = reg[33 * 64 + lane];
    float mM = fmaxf(mrow, mB);
    float alpha = exp2f(mrow - mM);
    float beta  = exp2f(mB - mM);
    float linv = 1.0f / (alpha * lrow + beta * lB);
#pragma unroll
    for (int rg = 0; rg < 16; ++rg) {
      int rs = (rg & 3) + 8 * (rg >> 2) + 4 * h;
      float a  = __shfl(alpha, rs);
      float b  = __shfl(beta, rs);
      float li = __shfl(linv, rs);
      float o0 = (a * acc0[rg] + b * reg[rg * 64 + lane]) * li;
      float o1 = (a * acc1[rg] + b * reg[(16 + rg) * 64 + lane]) * li;
      size_t base = ((size_t)bh * SEQ + q0w + rs) * HD;
      att[base + l31]      = (bf16)o0;
      att[base + 32 + l31] = (bf16)o1;
    }
  }
}

extern "C" void kernel_launch(void* const* d_in, const int* in_sizes, int n_in,
                              void* d_out, int out_size, void* d_ws, size_t ws_size,
                              hipStream_t stream) {
  const float* x  = (const float*)d_in[0];
  const int* pos  = (const int*)d_in[1];
  const float* Wq = (const float*)d_in[2];
  const float* Wk = (const float*)d_in[3];
  const float* Wv = (const float*)d_in[4];
  const float* Wo = (const float*)d_in[5];
  float* out = (float*)d_out;

  char* p = (char*)d_ws;
  bf16* xb   = (bf16*)p; p += (size_t)MTOT * DM * 2;
  bf16* wqb  = (bf16*)p; p += (size_t)DM * DM * 2;
  bf16* wkb  = (bf16*)p; p += (size_t)DM * DM * 2;
  bf16* wvb  = (bf16*)p; p += (size_t)DM * DM * 2;
  bf16* wob  = (bf16*)p; p += (size_t)DM * DM * 2;
  bf16* qb   = (bf16*)p; p += (size_t)MTOT * DM * 2;
  bf16* kb   = (bf16*)p; p += (size_t)MTOT * DM * 2;
  bf16* vtb  = (bf16*)p; p += (size_t)MTOT * DM * 2;
  bf16* attb = (bf16*)p; p += (size_t)MTOT * DM * 2;
  float2* tab = (float2*)p; p += (size_t)MTOT * 32 * sizeof(float2);
  (void)wkb; (void)wvb;

  prep_kernel<<<(2097152 + 131072 + 255) / 256, 256, 0, stream>>>(
      x, Wq, Wk, Wv, Wo, pos, xb, wqb, tab);

  gemm_qkv<<<dim3(24, MTOT / 128), 512, 0, stream>>>(xb, wqb, qb, kb, vtb, tab);

  attn_kernel<<<512, 512, 0, stream>>>(qb, kb, vtb, attb);

  gemm_out<<<dim3(DM / 64, MTOT / 64), 256, 0, stream>>>(attb, wob, out);
}